// Round 5
// baseline (789.840 us; speedup 1.0000x reference)
//
#include <hip/hip_runtime.h>
#include <math.h>

#define NEG_INF (-3.402823466e+38f)

typedef __attribute__((ext_vector_type(8))) short short8;
typedef __attribute__((ext_vector_type(8))) unsigned short ushort8;
typedef __attribute__((ext_vector_type(4))) float f32x4;

// ---- dims ----
constexpr int NTOK = 4608;              // 2560 Q + 768 Wp + 256 Rp + 768 Wr + 256 Rr
constexpr int BH = 64 * 256;            // one (b,u) plane

// ---- ws offsets (floats); ushort arrays use 2 elems per float slot ----
constexpr size_t OFF_WQ    = 0;                          // 524288 fl (= WHB 1048576 ush)
constexpr size_t OFF_B2    = OFF_WQ    + 524288;         // 2048
constexpr size_t OFF_XB3T  = OFF_B2    + 2048;           // 2048*960 us  = 983040 fl
constexpr size_t OFF_WB3T  = OFF_XB3T  + 983040;         // 512*1536 us  = 393216 fl
constexpr size_t OFF_L2B3T = OFF_WB3T  + 393216;         // 393216 fl
constexpr size_t OFF_C1B3T = OFF_L2B3T + 393216;         // 192*3072 us  = 294912 fl
constexpr size_t OFF_C2B3T = OFF_C1B3T + 294912;         // 192*9216 us  = 884736 fl
constexpr size_t OFF_C3B3T = OFF_C2B3T + 884736;         // 192*15360 us = 1474560 fl
constexpr size_t OFF_XHI   = OFF_C3B3T + 1474560;        // 4608*320 us  = 737280 fl
constexpr size_t OFF_XLO   = OFF_XHI   + 737280;
constexpr size_t OFF_XP    = OFF_XLO   + 737280;         // 4608*2048 fp32 = 9437184
constexpr size_t OFF_HSQ   = OFF_XP    + 9437184;        // 1310720
constexpr size_t OFF_HSWP  = OFF_HSQ   + 1310720;        // 393216
constexpr size_t OFF_HSRP  = OFF_HSWP  + 393216;         // 131072
constexpr size_t OFF_HSWR  = OFF_HSRP  + 131072;         // 393216
constexpr size_t OFF_HSRR  = OFF_HSWR  + 393216;         // 131072
constexpr size_t OFF_CS    = OFF_HSRR  + 131072;         // 163840 (during steps: bar counters)
constexpr size_t OFF_RELP  = OFF_CS    + 163840;         // 524288 (during steps: Hhi/Hlo planes)
constexpr size_t OFF_RELC  = OFF_RELP  + 524288;         // 524288
constexpr size_t OFF_RELW  = OFF_RELC  + 524288;         // 524288
constexpr size_t OFF_EN    = OFF_RELW  + 524288;         // 40960
// end = OFF_EN + 40960 = 19998720 floats (~80 MB)
// XP region aliases (XP dead after k_steps):
//   QO1 +0 (1310720), ATT +1310720, QO2 +2621440,
//   Dhi +3932160 (655360 fl), Dlo +4587520,
//   RPhi +5242880, RPlo +5505024, RChi +5767168, RClo +6029312 (dead before k_m2)
//   M2hi +5242880 (1313024 fl), M2lo +6555904,
//   Y1 +7868928, Y2 +8360448, Y3 +8851968 (end 9343488 < 9437184)

__device__ inline unsigned short f2bf(float f) {
  unsigned int u = __float_as_uint(f);
  u += 0x7FFFu + ((u >> 16) & 1u);          // RNE
  return (unsigned short)(u >> 16);
}
__device__ inline float bf2f(unsigned short h) {
  return __uint_as_float(((unsigned int)h) << 16);
}
__device__ inline short8 mk8(unsigned long long a, unsigned long long b) {
  union { unsigned long long q[2]; short8 s; } u;
  u.q[0] = a; u.q[1] = b; return u.s;
}
#define ALD(p) __hip_atomic_load((p), __ATOMIC_RELAXED, __HIP_MEMORY_SCOPE_AGENT)

// ================= prep: WHB (tile16 gate-interleaved Whh bf16 hi|lo) + bias + B3T =====
// WHB layout: [dir][tile 16][row = g*16+uu (64)][hi k 0..255 | lo k 0..255]
__global__ __launch_bounds__(256) void k_prep(
    const float* __restrict__ Whh_f, const float* __restrict__ Whh_b,
    const float* __restrict__ b_f,   const float* __restrict__ b_b,
    const float* __restrict__ Wih_f, const float* __restrict__ Wih_b,
    const float* __restrict__ Wat,   const float* __restrict__ l2w,
    const float* __restrict__ c1w, const float* __restrict__ c2w, const float* __restrict__ c3w,
    unsigned short* __restrict__ WHB, float* __restrict__ B2,
    unsigned short* __restrict__ XB3T, unsigned short* __restrict__ WB3T,
    unsigned short* __restrict__ L2B3T,
    unsigned short* __restrict__ C1B3T, unsigned short* __restrict__ C2B3T,
    unsigned short* __restrict__ C3B3T, int* __restrict__ bar) {
  if (blockIdx.x == 0 && threadIdx.x < 8)       // reset chain barriers at the coherence point
    __hip_atomic_store(bar + threadIdx.x, 0, __ATOMIC_RELAXED, __HIP_MEMORY_SCOPE_AGENT);
  int idx = blockIdx.x * 256 + threadIdx.x;
  if (idx < 1048576) {                      // WHB
    int e = idx & 511;                      // k + 256*isLo
    int k = e & 255, isLo = e >> 8;
    int row = (idx >> 9) & 63;              // g*16+uu
    int tile = (idx >> 15) & 15;
    int d = idx >> 19;
    int g = row >> 4, uu = row & 15;
    int u = tile * 16 + uu;
    const float* Wh = d ? Whh_b : Whh_f;
    float w = Wh[(size_t)(g * 256 + u) * 256 + k];
    unsigned short hi = f2bf(w);
    WHB[idx] = isLo ? f2bf(w - bf2f(hi)) : hi;
    return;
  }
  idx -= 1048576;
  if (idx < 2048) { B2[idx] = (idx < 1024) ? b_f[idx] : b_b[idx-1024]; return; }
  idx -= 2048;
  unsigned short* dst; int n, k, K;
  float w;
  if (idx < 655360) {                       // XB3T: n<2048, Kp=320 (src K=300)
    n = idx / 320; k = idx % 320; K = 320; dst = XB3T;
    w = (k < 300) ? ((n < 1024) ? Wih_f[(size_t)n*300 + k] : Wih_b[(size_t)(n-1024)*300 + k]) : 0.f;
  } else if ((idx -= 655360) < 262144) {    // WB3T: B[k][n] = Wat[k][n]
    n = idx >> 9; k = idx & 511; K = 512; dst = WB3T;
    w = Wat[(size_t)k*512 + n];
  } else if ((idx -= 262144) < 262144) {    // L2B3T: B[k][n] = l2w[n][k]
    n = idx >> 9; k = idx & 511; K = 512; dst = L2B3T;
    w = l2w[(size_t)n*512 + k];
  } else if ((idx -= 262144) < 196608) {    // C1B3T (n pad 192)
    n = idx >> 10; k = idx & 1023; K = 1024; dst = C1B3T;
    w = (n < 150) ? c1w[(size_t)n*1024 + k] : 0.f;
  } else if ((idx -= 196608) < 589824) {    // C2B3T
    n = idx / 3072; k = idx % 3072; K = 3072; dst = C2B3T;
    int kw = k >> 10, c = k & 1023;
    w = (n < 150) ? c2w[((size_t)n*1024 + c)*3 + kw] : 0.f;
  } else if ((idx -= 589824) < 983040) {    // C3B3T
    n = idx / 5120; k = idx % 5120; K = 5120; dst = C3B3T;
    int kw = k >> 10, c = k & 1023;
    w = (n < 150) ? c3w[((size_t)n*1024 + c)*5 + kw] : 0.f;
  } else return;
  unsigned short hi = f2bf(w);
  unsigned short lo = f2bf(w - bf2f(hi));
  size_t base = (size_t)n * (3*K);
  dst[base + k] = hi;
  dst[base + K + k] = lo;
  dst[base + 2*K + k] = hi;
}

// ================= gather embeddings -> bf16 split, K padded to 320 =================
__global__ __launch_bounds__(320) void k_gather(
    const int* __restrict__ q,  const int* __restrict__ wr, const int* __restrict__ rr,
    const int* __restrict__ wp, const int* __restrict__ rp,
    const float* __restrict__ we, const float* __restrict__ re,
    unsigned short* __restrict__ Xhi, unsigned short* __restrict__ Xlo) {
  int m = blockIdx.x, k = threadIdx.x;
  const float* emb; int row;
  if (m < 2560)      { int t=m>>6,    b=m&63; row = q [b*40+t]; emb = we; }
  else if (m < 3328) { int mm=m-2560; int t=mm>>6,b=mm&63; row = wp[b*12+t]; emb = we; }
  else if (m < 3584) { int mm=m-3328; int t=mm>>6,b=mm&63; row = rp[b*4 +t]; emb = re; }
  else if (m < 4352) { int mm=m-3584; int t=mm>>6,b=mm&63; row = wr[b*12+t]; emb = we; }
  else               { int mm=m-4352; int t=mm>>6,b=mm&63; row = rr[b*4 +t]; emb = re; }
  float v = (k < 300) ? emb[(size_t)row*300 + k] : 0.f;
  unsigned short hi = f2bf(v);
  Xhi[(size_t)m*320 + k] = hi;
  Xlo[(size_t)m*320 + k] = f2bf(v - bf2f(hi));
}

// ===== MFMA GEMM (bf16 3-split): C[M][N] = sum over 3K of Asel[m][kk] * Bt[n][k0] =====
template<bool BIAS>
__global__ __launch_bounds__(256) void k_mgemm(
    const unsigned short* __restrict__ Ahi, const unsigned short* __restrict__ Alo, int lda,
    const unsigned short* __restrict__ Bt, const float* __restrict__ bias,
    float* __restrict__ C, int N, int K) {
  __shared__ unsigned short As[64 * 40];   // rows padded to 40 ushorts (80 B)
  __shared__ unsigned short Bs[64 * 40];
  int tid = threadIdx.x;
  int wave = tid >> 6, lane = tid & 63;
  int quad = lane >> 4, l16 = lane & 15;
  int m0 = blockIdx.x << 6, n0 = blockIdx.y << 6;
  int K3 = 3 * K;
  int sr = tid >> 2;               // staging row 0..63
  int sc = (tid & 3) << 3;         // staging col 0,8,16,24
  f32x4 acc[4] = {};
  for (int k0 = 0; k0 < K3; k0 += 32) {
    int c = (k0 >= K) + (k0 >= 2*K);
    const unsigned short* Asrc = (c == 2) ? Alo : Ahi;
    int kk = k0 - c * K;
    ushort8 av = *(const ushort8*)(Asrc + (size_t)(m0 + sr) * lda + kk + sc);
    ushort8 bv = *(const ushort8*)(Bt + (size_t)(n0 + sr) * K3 + k0 + sc);
    *(ushort8*)&As[sr * 40 + sc] = av;
    *(ushort8*)&Bs[sr * 40 + sc] = bv;
    __syncthreads();
    short8 a  = *(const short8*)&As[(wave*16 + l16) * 40 + quad*8];
    short8 b0 = *(const short8*)&Bs[( 0 + l16) * 40 + quad*8];
    short8 b1 = *(const short8*)&Bs[(16 + l16) * 40 + quad*8];
    short8 b2 = *(const short8*)&Bs[(32 + l16) * 40 + quad*8];
    short8 b3 = *(const short8*)&Bs[(48 + l16) * 40 + quad*8];
    acc[0] = __builtin_amdgcn_mfma_f32_16x16x32_bf16(a, b0, acc[0], 0, 0, 0);
    acc[1] = __builtin_amdgcn_mfma_f32_16x16x32_bf16(a, b1, acc[1], 0, 0, 0);
    acc[2] = __builtin_amdgcn_mfma_f32_16x16x32_bf16(a, b2, acc[2], 0, 0, 0);
    acc[3] = __builtin_amdgcn_mfma_f32_16x16x32_bf16(a, b3, acc[3], 0, 0, 0);
    __syncthreads();
  }
  int row0 = m0 + wave * 16 + quad * 4;    // C/D: col=lane&15, row=quad*4+reg
#pragma unroll
  for (int t = 0; t < 4; t++) {
    int col = n0 + t * 16 + l16;
    float bb = BIAS ? bias[col] : 0.f;
#pragma unroll
    for (int r = 0; r < 4; r++)
      C[(size_t)(row0 + r) * N + col] = acc[t][r] + bb;
  }
}

// ===== fused conv GEMMs, split-K, atomic accumulate into zeroed Y =====
// blockIdx.z: [0,4) conv1 split, [4,12) conv2 split, [12,20) conv3 split
__global__ __launch_bounds__(256) void k_cgemm(
    const unsigned short* __restrict__ Ahi, const unsigned short* __restrict__ Alo,
    const unsigned short* __restrict__ B1, const unsigned short* __restrict__ B2c,
    const unsigned short* __restrict__ B3,
    float* __restrict__ Y1, float* __restrict__ Y2, float* __restrict__ Y3) {
  __shared__ unsigned short As[64 * 40];
  __shared__ unsigned short Bs[64 * 40];
  int z = blockIdx.z;
  const unsigned short* Bt; float* Y; int K, sidx, chunk;
  if (z < 4)       { Bt = B1;  Y = Y1; K = 1024; sidx = z;      chunk = 768;  }
  else if (z < 12) { Bt = B2c; Y = Y2; K = 3072; sidx = z - 4;  chunk = 1152; }
  else             { Bt = B3;  Y = Y3; K = 5120; sidx = z - 12; chunk = 1920; }
  int K3 = 3 * K;
  int ks = sidx * chunk, ke = ks + chunk;
  int tid = threadIdx.x;
  int wave = tid >> 6, lane = tid & 63;
  int quad = lane >> 4, l16 = lane & 15;
  int m0 = blockIdx.x << 6, n0 = blockIdx.y << 6;
  int sr = tid >> 2;
  int sc = (tid & 3) << 3;
  f32x4 acc[4] = {};
  for (int k0 = ks; k0 < ke; k0 += 32) {
    int c = (k0 >= K) + (k0 >= 2*K);
    const unsigned short* Asrc = (c == 2) ? Alo : Ahi;
    int kk = k0 - c * K;
    ushort8 av = *(const ushort8*)(Asrc + (size_t)(m0 + sr) * 1024 + kk + sc);
    ushort8 bv = *(const ushort8*)(Bt + (size_t)(n0 + sr) * K3 + k0 + sc);
    *(ushort8*)&As[sr * 40 + sc] = av;
    *(ushort8*)&Bs[sr * 40 + sc] = bv;
    __syncthreads();
    short8 a  = *(const short8*)&As[(wave*16 + l16) * 40 + quad*8];
    short8 b0 = *(const short8*)&Bs[( 0 + l16) * 40 + quad*8];
    short8 b1 = *(const short8*)&Bs[(16 + l16) * 40 + quad*8];
    short8 b2 = *(const short8*)&Bs[(32 + l16) * 40 + quad*8];
    short8 b3 = *(const short8*)&Bs[(48 + l16) * 40 + quad*8];
    acc[0] = __builtin_amdgcn_mfma_f32_16x16x32_bf16(a, b0, acc[0], 0, 0, 0);
    acc[1] = __builtin_amdgcn_mfma_f32_16x16x32_bf16(a, b1, acc[1], 0, 0, 0);
    acc[2] = __builtin_amdgcn_mfma_f32_16x16x32_bf16(a, b2, acc[2], 0, 0, 0);
    acc[3] = __builtin_amdgcn_mfma_f32_16x16x32_bf16(a, b3, acc[3], 0, 0, 0);
    __syncthreads();
  }
  int row0 = m0 + wave * 16 + quad * 4;
#pragma unroll
  for (int t = 0; t < 4; t++) {
    int col = n0 + t * 16 + l16;
#pragma unroll
    for (int r = 0; r < 4; r++)
      atomicAdd(&Y[(size_t)(row0 + r) * 192 + col], acc[t][r]);
  }
}

// ================= zero a float region (Y partial-sum init) =================
__global__ __launch_bounds__(256) void k_zero(float* __restrict__ p, int n4) {
  int idx = blockIdx.x * 256 + threadIdx.x;
  if (idx < n4) *(float4*)(p + (size_t)idx * 4) = make_float4(0.f, 0.f, 0.f, 0.f);
}

// ========== persistent recurrent kernel v3: zero LDS, weights in VGPRs ==========
// 128 blocks; chain = bid&7 (0..5 active), tile = bid>>3 (0..15).
// Per block: M=64 batches x N=64 (4 gates x 16 u) x K=256, bf16x3.
// Weights (B-frags, step-invariant) live in registers: Bh[4][8] + Bl[4][8] short8.
// h exchanged via TWO sc1 ushort planes (hi,lo) so a 16B load IS an A-frag directly.
// No __shared__ at all; barriers only order the sc1 exchange.
__global__ __launch_bounds__(256, 1) void k_steps(
    const unsigned short* __restrict__ WHB, const float* __restrict__ XP,
    float* __restrict__ hsQ, float* __restrict__ hsWp, float* __restrict__ hsRp,
    float* __restrict__ hsWr, float* __restrict__ hsRr,
    unsigned short* __restrict__ Hhi, unsigned short* __restrict__ Hlo,
    int* __restrict__ bar) {
  int bid = blockIdx.x;
  int chain = bid & 7;
  if (chain >= 6) return;                // 2 of 8 xcd-slots idle
  int tile = bid >> 3;                   // 0..15
  int dir = chain & 1, fam = chain >> 1;
  int tid = threadIdx.x;
  int wave = tid >> 6, lane = tid & 63;
  int quad = lane >> 4, l16 = lane & 15;
  int u0 = tile << 4;

  // ---- load weight B-fragments into registers once (step-invariant) ----
  const unsigned short* wsrc = WHB + (((size_t)dir * 16 + tile) << 15);   // 64 rows x 512
  short8 Bh[4][8], Bl[4][8];
#pragma unroll
  for (int nf = 0; nf < 4; nf++)
#pragma unroll
    for (int j = 0; j < 8; j++) {
      const unsigned short* wr = wsrc + (nf * 16 + l16) * 512 + j * 32 + quad * 8;
      Bh[nf][j] = *(const short8*)(wr);
      Bl[nf][j] = *(const short8*)(wr + 256);
    }

  int nsteps = (fam == 0) ? 40 : 16;
  float creg[4] = {0.f, 0.f, 0.f, 0.f};
  int row64 = (wave * 16 + l16) * 64 + quad * 2;   // u64 index of this lane's A-frag row base

  for (int cs = 0; cs < nsteps; cs++) {
    // ---- phase params + XP prefetch (issued before the barrier wait) ----
    int t, T, seg; float* hsb;
    if (fam == 0)     { t = cs;      T = 40; seg = 0;                         hsb = hsQ + (size_t)dir * 40 * BH; }
    else if (cs < 12) { t = cs;      T = 12; seg = (fam == 1) ? 2560 : 3584;  hsb = ((fam == 1) ? hsWp : hsWr) + (size_t)dir * 12 * BH; }
    else              { t = cs - 12; T = 4;  seg = (fam == 1) ? 3328 : 4352;  hsb = ((fam == 1) ? hsRp : hsRr) + (size_t)dir * 4 * BH; }
    int t_in = dir ? (T - 1 - t) : t;
    int u = u0 + l16;
    const float* xb = XP + (size_t)(seg + t_in * 64) * 2048 + dir * 1024 + u;
    float xi[4], xf[4], xg[4], xo[4];
#pragma unroll
    for (int r = 0; r < 4; r++) {
      const float* xr = xb + (size_t)(wave * 16 + quad * 4 + r) * 2048;
      xi[r] = xr[0]; xf[r] = xr[256]; xg[r] = xr[512]; xo[r] = xr[768];
    }

    f32x4 acc[4] = {};
    if (cs > 0) {
      if (tid == 0) {
        int tgt = 16 * cs;
        while (__hip_atomic_load(bar + chain, __ATOMIC_RELAXED, __HIP_MEMORY_SCOPE_AGENT) < tgt)
          __builtin_amdgcn_s_sleep(1);
      }
      __syncthreads();
      // ---- coherent h load, direct to A-frags (hi plane + lo plane) ----
      size_t slotq = (size_t)(chain * 2 + ((cs - 1) & 1)) * 4096;   // u64 units (16384 ush)
      const unsigned long long* ph = (const unsigned long long*)Hhi + slotq + row64;
      const unsigned long long* pl = (const unsigned long long*)Hlo + slotq + row64;
      unsigned long long rv[32];
#pragma unroll
      for (int j = 0; j < 8; j++) { rv[2*j] = ALD(ph + 8*j); rv[2*j+1] = ALD(ph + 8*j + 1); }
#pragma unroll
      for (int j = 0; j < 8; j++) { rv[16+2*j] = ALD(pl + 8*j); rv[16+2*j+1] = ALD(pl + 8*j + 1); }
      short8 ah[8], al[8];
#pragma unroll
      for (int j = 0; j < 8; j++) { ah[j] = mk8(rv[2*j], rv[2*j+1]); al[j] = mk8(rv[16+2*j], rv[16+2*j+1]); }
      // ---- bf16x3, all operands in registers ----
#pragma unroll
      for (int j = 0; j < 8; j++) {
        acc[0] = __builtin_amdgcn_mfma_f32_16x16x32_bf16(ah[j], Bh[0][j], acc[0], 0, 0, 0);
        acc[1] = __builtin_amdgcn_mfma_f32_16x16x32_bf16(ah[j], Bh[1][j], acc[1], 0, 0, 0);
        acc[2] = __builtin_amdgcn_mfma_f32_16x16x32_bf16(ah[j], Bh[2][j], acc[2], 0, 0, 0);
        acc[3] = __builtin_amdgcn_mfma_f32_16x16x32_bf16(ah[j], Bh[3][j], acc[3], 0, 0, 0);
      }
#pragma unroll
      for (int j = 0; j < 8; j++) {
        acc[0] = __builtin_amdgcn_mfma_f32_16x16x32_bf16(ah[j], Bl[0][j], acc[0], 0, 0, 0);
        acc[1] = __builtin_amdgcn_mfma_f32_16x16x32_bf16(ah[j], Bl[1][j], acc[1], 0, 0, 0);
        acc[2] = __builtin_amdgcn_mfma_f32_16x16x32_bf16(ah[j], Bl[2][j], acc[2], 0, 0, 0);
        acc[3] = __builtin_amdgcn_mfma_f32_16x16x32_bf16(ah[j], Bl[3][j], acc[3], 0, 0, 0);
      }
#pragma unroll
      for (int j = 0; j < 8; j++) {
        acc[0] = __builtin_amdgcn_mfma_f32_16x16x32_bf16(al[j], Bh[0][j], acc[0], 0, 0, 0);
        acc[1] = __builtin_amdgcn_mfma_f32_16x16x32_bf16(al[j], Bh[1][j], acc[1], 0, 0, 0);
        acc[2] = __builtin_amdgcn_mfma_f32_16x16x32_bf16(al[j], Bh[2][j], acc[2], 0, 0, 0);
        acc[3] = __builtin_amdgcn_mfma_f32_16x16x32_bf16(al[j], Bh[3][j], acc[3], 0, 0, 0);
      }
    }
    // ---- gates + state update (acc frag nf = gate; row = batch; col = u) ----
    float* hout = hsb + (size_t)t * BH + u;
    size_t oslot = (size_t)(chain * 2 + (cs & 1)) << 14;
    unsigned short* oh = Hhi + oslot;
    unsigned short* ol = Hlo + oslot;
#pragma unroll
    for (int r = 0; r < 4; r++) {
      int b = wave * 16 + quad * 4 + r;
      float zi = acc[0][r] + xi[r];
      float zf = acc[1][r] + xf[r];
      float zg = acc[2][r] + xg[r];
      float zo = acc[3][r] + xo[r];
      float gi = 1.f / (1.f + expf(-zi));
      float gf = 1.f / (1.f + expf(-zf));
      float go = 1.f / (1.f + expf(-zo));
      float gg = tanhf(zg);
      float cn = gf * creg[r] + gi * gg;
      float hn = go * tanhf(cn);
      creg[r] = cn;
      unsigned short h16 = f2bf(hn);
      unsigned short l16v = f2bf(hn - bf2f(h16));
      unsigned int pk = (unsigned int)h16 | ((unsigned int)l16v << 16);
      unsigned int pw = (unsigned int)__shfl_xor((int)pk, 1, 64);   // partner lane (u^1)
      if ((lane & 1) == 0) {
        unsigned int hw = (pk & 0xFFFFu) | (pw << 16);              // hi(u), hi(u+1)
        unsigned int lw = (pk >> 16) | (pw & 0xFFFF0000u);          // lo(u), lo(u+1)
        __hip_atomic_store((unsigned int*)(oh + b * 256 + u), hw,
                           __ATOMIC_RELAXED, __HIP_MEMORY_SCOPE_AGENT);
        __hip_atomic_store((unsigned int*)(ol + b * 256 + u), lw,
                           __ATOMIC_RELAXED, __HIP_MEMORY_SCOPE_AGENT);
      }
      hout[(size_t)b * 256] = hn;
    }
    if (cs + 1 < nsteps) {
      __syncthreads();                  // drains vmcnt(0): sc1 stores ack'd at coherence point
      if (tid == 0)
        __hip_atomic_fetch_add(bar + chain, 1, __ATOMIC_RELAXED, __HIP_MEMORY_SCOPE_AGENT);
    }
  }
}

// ================= question_out as [b][s][h] =================
__global__ __launch_bounds__(256) void k_qo1(const float* __restrict__ hsQ, float* __restrict__ QT) {
  int idx = blockIdx.x * 256 + threadIdx.x;
  if (idx >= 64*40*512) return;
  int h = idx & 511; int t2 = idx >> 9; int s = t2 % 40; int b = t2 / 40;
  float v;
  if (h < 256) v = hsQ[(size_t)s * BH + b*256 + h];
  else         v = hsQ[(size_t)40 * BH + (size_t)(39 - s) * BH + b*256 + (h - 256)];
  QT[idx] = v;
}

// ================= relation tensors [b][r][h] fp32 + bf16-split, both calls ==============
__global__ __launch_bounds__(256) void k_rel(
    const float* __restrict__ hsWp, const float* __restrict__ hsRp,
    const float* __restrict__ hsWr, const float* __restrict__ hsRr,
    float* __restrict__ RELP, float* __restrict__ RELC,
    unsigned short* __restrict__ RPhi, unsigned short* __restrict__ RPlo,
    unsigned short* __restrict__ RChi, unsigned short* __restrict__ RClo) {
  int idx0 = blockIdx.x * 256 + threadIdx.x;
  if (idx0 >= 2*64*16*512) return;
  int call = idx0 >= 64*16*512;
  int idx = idx0 - call * 64*16*512;
  int h = idx & 511; int t2 = idx >> 9; int r = t2 & 15; int b = t2 >> 4;
  const float* hsW = call ? hsWr : hsWp;
  const float* hsR = call ? hsRr : hsRp;
  float v;
  if (r < 4) {
    if (h < 256) v = hsR[(size_t)r * BH + b*256 + h];
    else         v = hsR[(size_t)4 * BH + (size_t)(3 - r) * BH + b*256 + (h - 256)];
  } else {
    int t = r - 4;
    if (h < 256) v = hsW[(size_t)t * BH + b*256 + h];
    else         v = hsW[(size_t)12 * BH + (size_t)(11 - t) * BH + b*256 + (h - 256)];
  }
  unsigned short hi = f2bf(v);
  unsigned short lo = f2bf(v - bf2f(hi));
  if (call) { RELC[idx] = v; RChi[idx] = hi; RClo[idx] = lo; }
  else      { RELP[idx] = v; RPhi[idx] = hi; RPlo[idx] = lo; }
}

// ================= energy[b][r][s] =================
__global__ __launch_bounds__(256) void k_energy(
    const float* __restrict__ relW, const float* __restrict__ QT, float* __restrict__ EN) {
  int idx = blockIdx.x * 256 + threadIdx.x;
  if (idx >= 64*16*40) return;
  int s = idx % 40; int t = idx / 40; int r = t & 15; int b = t >> 4;
  const float* rw = relW + (size_t)(b*16 + r) * 512;
  const float* qv = QT   + (size_t)(b*40 + s) * 512;
  float acc = 0.f;
#pragma unroll 4
  for (int k = 0; k < 512; k += 4) {
    float4 a = *(const float4*)(rw + k);
    float4 c = *(const float4*)(qv + k);
    acc += a.x*c.x + a.y*c.y + a.z*c.z + a.w*c.w;
  }
  EN[idx] = acc;
}

// ================= softmax over 640 per b =================
__global__ __launch_bounds__(256) void k_softmax(float* __restrict__ EN) {
  int b = blockIdx.x; int tid = threadIdx.x;
  float* e = EN + b * 640;
  float v0 = e[tid] * 0.25f, v1 = e[tid + 256] * 0.25f;
  float v2 = (tid < 128) ? e[tid + 512] * 0.25f : NEG_INF;
  __shared__ float sh[256];
  sh[tid] = fmaxf(v0, fmaxf(v1, v2));
  __syncthreads();
  for (int st = 128; st > 0; st >>= 1) { if (tid < st) sh[tid] = fmaxf(sh[tid], sh[tid+st]); __syncthreads(); }
  float m = sh[0];
  __syncthreads();
  float e0 = expf(v0 - m), e1 = expf(v1 - m);
  float e2 = (tid < 128) ? expf(v2 - m) : 0.f;
  sh[tid] = e0 + e1 + e2;
  __syncthreads();
  for (int st = 128; st > 0; st >>= 1) { if (tid < st) sh[tid] += sh[tid+st]; __syncthreads(); }
  float inv = 1.f / sh[0];
  e[tid] = e0 * inv; e[tid + 256] = e1 * inv;
  if (tid < 128) e[tid + 512] = e2 * inv;
}

// ================= atten[b][s][h] =================
__global__ __launch_bounds__(256) void k_atten(
    const float* __restrict__ AL, const float* __restrict__ REL, float* __restrict__ ATT) {
  int idx = blockIdx.x * 256 + threadIdx.x;
  if (idx >= 64*40*512) return;
  int h = idx & 511; int t2 = idx >> 9; int s = t2 % 40; int b = t2 / 40;
  const float* al = AL + b * 640 + s;
  const float* rl = REL + (size_t)b * 16 * 512 + h;
  float acc = 0.f;
#pragma unroll
  for (int r = 0; r < 16; r++) acc += al[r*40] * rl[r*512];
  ATT[idx] = acc;
}

// ================= (QT - ATT) -> bf16 split =================
__global__ __launch_bounds__(256) void k_sub(
    const float* __restrict__ QT, const float* __restrict__ ATT,
    unsigned short* __restrict__ Dhi, unsigned short* __restrict__ Dlo) {
  int idx = blockIdx.x * 256 + threadIdx.x;
  if (idx >= 64*40*512) return;
  float v = QT[idx] - ATT[idx];
  unsigned short hi = f2bf(v);
  Dhi[idx] = hi; Dlo[idx] = f2bf(v - bf2f(hi));
}

// ================= pack M2[m][c] bf16-split, with zero tail pad =================
__global__ __launch_bounds__(256) void k_m2(
    const float* __restrict__ QO2, const float* __restrict__ ATT,
    unsigned short* __restrict__ M2hi, unsigned short* __restrict__ M2lo) {
  int idx = blockIdx.x * 256 + threadIdx.x;
  if (idx >= 2626048) return;
  float v = 0.f;
  if (idx < 2621440) {
    int c = idx & 1023; int m = idx >> 10;
    v = (c < 512) ? QO2[(size_t)m*512 + c] : ATT[(size_t)m*512 + (c - 512)];
  }
  unsigned short hi = f2bf(v);
  M2hi[idx] = hi; M2lo[idx] = f2bf(v - bf2f(hi));
}

// ================= pool(bias+relu+max over l) + score =================
__global__ __launch_bounds__(256) void k_pool(
    const float* __restrict__ Y1, const float* __restrict__ Y2, const float* __restrict__ Y3,
    const float* __restrict__ b1, const float* __restrict__ b2, const float* __restrict__ b3,
    const float* __restrict__ lw, float* __restrict__ out) {
  int b = blockIdx.x, o = threadIdx.x;
  float hv = 0.f;
  if (o < 150) {
    const float* y1 = Y1 + (size_t)b*40*192 + o;
    const float* y2 = Y2 + (size_t)b*40*192 + o;
    const float* y3 = Y3 + (size_t)b*40*192 + o;
    float m1 = NEG_INF, m2 = NEG_INF, m3 = NEG_INF;
#pragma unroll 4
    for (int l = 0; l < 40; l++) m1 = fmaxf(m1, y1[l*192]);
#pragma unroll 2
    for (int l = 0; l < 38; l++) m2 = fmaxf(m2, y2[l*192]);
#pragma unroll 2
    for (int l = 0; l < 36; l++) m3 = fmaxf(m3, y3[l*192]);
    float h = fmaxf(fmaxf(m1 + b1[o], m2 + b2[o]), m3 + b3[o]);
    hv = fmaxf(h, 0.f) * lw[o];
  }
  __shared__ float sh[256];
  sh[threadIdx.x] = hv;
  __syncthreads();
  for (int st = 128; st > 0; st >>= 1) { if (threadIdx.x < st) sh[threadIdx.x] += sh[threadIdx.x+st]; __syncthreads(); }
  if (threadIdx.x == 0) out[b] = sh[0];
}

// ================= host =================
extern "C" void kernel_launch(void* const* d_in, const int* in_sizes, int n_in,
                              void* d_out, int out_size, void* d_ws, size_t ws_size,
                              hipStream_t stream) {
  const int*   q    = (const int*)d_in[0];
  const int*   wrel = (const int*)d_in[1];
  const int*   rrel = (const int*)d_in[2];
  const int*   wprv = (const int*)d_in[3];
  const int*   rprv = (const int*)d_in[4];
  const float* we   = (const float*)d_in[5];
  const float* re   = (const float*)d_in[6];
  const float* Wih_f= (const float*)d_in[7];
  const float* Whh_f= (const float*)d_in[8];
  const float* b_f  = (const float*)d_in[9];
  const float* Wih_b= (const float*)d_in[10];
  const float* Whh_b= (const float*)d_in[11];
  const float* b_b  = (const float*)d_in[12];
  const float* W    = (const float*)d_in[13];
  const float* c1w  = (const float*)d_in[14];
  const float* c1b  = (const float*)d_in[15];
  const float* c2w  = (const float*)d_in[16];
  const float* c2b  = (const float*)d_in[17];
  const float* c3w  = (const float*)d_in[18];
  const float* c3b  = (const float*)d_in[19];
  const float* lw   = (const float*)d_in[20];
  const float* l2w  = (const float*)d_in[21];
  const float* l2b  = (const float*)d_in[22];
  float* out = (float*)d_out;
  float* ws  = (float*)d_ws;

  unsigned short* WHB = (unsigned short*)(ws + OFF_WQ);   // 1048576 ush (exact fit)
  float* B2   = ws + OFF_B2;
  unsigned short* XB3T  = (unsigned short*)(ws + OFF_XB3T);
  unsigned short* WB3T  = (unsigned short*)(ws + OFF_WB3T);
  unsigned short* L2B3T = (unsigned short*)(ws + OFF_L2B3T);
  unsigned short* C1B3T = (unsigned short*)(ws + OFF_C1B3T);
  unsigned short* C2B3T = (unsigned short*)(ws + OFF_C2B3T);
  unsigned short* C3B3T = (unsigned short*)(ws + OFF_C3B3T);
  unsigned short* Xhi   = (unsigned short*)(ws + OFF_XHI);
  unsigned short* Xlo   = (unsigned short*)(ws + OFF_XLO);
  float* XP   = ws + OFF_XP;
  float* HSQ  = ws + OFF_HSQ;
  float* HSWP = ws + OFF_HSWP;
  float* HSRP = ws + OFF_HSRP;
  float* HSWR = ws + OFF_HSWR;
  float* HSRR = ws + OFF_HSRR;
  int*   bar  = (int*)(ws + OFF_CS);                      // CS region repurposed
  float* RELP = ws + OFF_RELP;
  float* RELC = ws + OFF_RELC;
  float* RELW = ws + OFF_RELW;
  float* EN   = ws + OFF_EN;
  // During the step loop, the RELP region holds the h planes:
  // Hhi [6 chain][2 parity][64 b][256 u] ush = 196608 ush; Hlo same after = 393216 ush total
  // = 196608 fl < 524288 fl.
  unsigned short* Hhi = (unsigned short*)(ws + OFF_RELP);
  unsigned short* Hlo = Hhi + 196608;
  // XP-region aliases (XP dead after k_steps)
  float* QO1  = XP;
  float* ATT  = XP + 1310720;
  float* QO2  = XP + 2621440;
  unsigned short* Dhi  = (unsigned short*)(XP + 3932160);
  unsigned short* Dlo  = (unsigned short*)(XP + 4587520);
  unsigned short* RPhi = (unsigned short*)(XP + 5242880);
  unsigned short* RPlo = (unsigned short*)(XP + 5505024);
  unsigned short* RChi = (unsigned short*)(XP + 5767168);
  unsigned short* RClo = (unsigned short*)(XP + 6029312);
  unsigned short* M2hi = (unsigned short*)(XP + 5242880);   // overwrites RP/RC (dead by then)
  unsigned short* M2lo = (unsigned short*)(XP + 6555904);
  float* Y1   = XP + 7868928;
  float* Y2   = XP + 8360448;
  float* Y3   = XP + 8851968;

  k_prep<<<15624, 256, 0, stream>>>(Whh_f, Whh_b, b_f, b_b, Wih_f, Wih_b, W, l2w,
                                    c1w, c2w, c3w,
                                    WHB, B2, XB3T, WB3T, L2B3T, C1B3T, C2B3T, C3B3T, bar);
  k_gather<<<NTOK, 320, 0, stream>>>(q, wrel, rrel, wprv, rprv, we, re, Xhi, Xlo);
  { dim3 g(72, 32); k_mgemm<true><<<g, 256, 0, stream>>>(Xhi, Xlo, 320, XB3T, B2, XP, 2048, 320); }

  // ---- all 40 recurrent steps in one persistent kernel (regs-only, sc1 exchange) ----
  k_steps<<<128, 256, 0, stream>>>(WHB, XP, HSQ, HSWP, HSRP, HSWR, HSRR, Hhi, Hlo, bar);

  k_qo1<<<5120, 256, 0, stream>>>(HSQ, QO1);
  k_rel<<<4096, 256, 0, stream>>>(HSWP, HSRP, HSWR, HSRR, RELP, RELC, RPhi, RPlo, RChi, RClo);

  // ---- attention (previous hop) ----
  { dim3 g(16, 8); k_mgemm<false><<<g, 256, 0, stream>>>(RPhi, RPlo, 512, WB3T, nullptr, RELW, 512, 512); }
  k_energy<<<160, 256, 0, stream>>>(RELW, QO1, EN);
  k_softmax<<<64, 256, 0, stream>>>(EN);
  k_atten<<<5120, 256, 0, stream>>>(EN, RELP, ATT);
  k_sub<<<5120, 256, 0, stream>>>(QO1, ATT, Dhi, Dlo);
  { dim3 g(40, 8); k_mgemm<true><<<g, 256, 0, stream>>>(Dhi, Dlo, 512, L2B3T, l2b, QO2, 512, 512); }

  // ---- attention (current relation) ----
  { dim3 g(16, 8); k_mgemm<false><<<g, 256, 0, stream>>>(RChi, RClo, 512, WB3T, nullptr, RELW, 512, 512); }
  k_energy<<<160, 256, 0, stream>>>(RELW, QO2, EN);
  k_softmax<<<64, 256, 0, stream>>>(EN);
  k_atten<<<5120, 256, 0, stream>>>(EN, RELC, ATT);

  // ---- convs: fused split-K MFMA GEMM, atomic accumulate into zeroed Y ----
  k_m2<<<10258, 256, 0, stream>>>(QO2, ATT, M2hi, M2lo);
  k_zero<<<1440, 256, 0, stream>>>(Y1, 368640);   // zero Y1..Y3 (contiguous 1474560 fl)
  { dim3 g(40, 3, 20); k_cgemm<<<g, 256, 0, stream>>>(M2hi, M2lo, C1B3T, C2B3T, C3B3T, Y1, Y2, Y3); }
  k_pool<<<64, 256, 0, stream>>>(Y1, Y2, Y3, c1b, c2b, c3b, lw, out);
}

// Round 6
// 785.145 us; speedup vs baseline: 1.0060x; 1.0060x over previous
//
#include <hip/hip_runtime.h>
#include <math.h>

#define NEG_INF (-3.402823466e+38f)

typedef __attribute__((ext_vector_type(8))) short short8;
typedef __attribute__((ext_vector_type(8))) unsigned short ushort8;
typedef __attribute__((ext_vector_type(4))) float f32x4;

// ---- dims ----
constexpr int NTOK = 4608;              // 2560 Q + 768 Wp + 256 Rp + 768 Wr + 256 Rr
constexpr int BH = 64 * 256;            // one (b,u) plane

// ---- ws offsets (floats); ushort arrays use 2 elems per float slot ----
constexpr size_t OFF_WQ    = 0;                          // 524288 fl (= WHB 1048576 ush)
constexpr size_t OFF_B2    = OFF_WQ    + 524288;         // 2048
constexpr size_t OFF_XB3T  = OFF_B2    + 2048;           // 2048*960 us  = 983040 fl
constexpr size_t OFF_WB3T  = OFF_XB3T  + 983040;         // 512*1536 us  = 393216 fl
constexpr size_t OFF_L2B3T = OFF_WB3T  + 393216;         // 393216 fl
constexpr size_t OFF_C1B3T = OFF_L2B3T + 393216;         // 192*3072 us  = 294912 fl
constexpr size_t OFF_C2B3T = OFF_C1B3T + 294912;         // 192*9216 us  = 884736 fl
constexpr size_t OFF_C3B3T = OFF_C2B3T + 884736;         // 192*15360 us = 1474560 fl
constexpr size_t OFF_XHI   = OFF_C3B3T + 1474560;        // 4608*320 us  = 737280 fl
constexpr size_t OFF_XLO   = OFF_XHI   + 737280;
constexpr size_t OFF_XP    = OFF_XLO   + 737280;         // 4608*2048 fp32 = 9437184
constexpr size_t OFF_HSQ   = OFF_XP    + 9437184;        // 1310720
constexpr size_t OFF_HSWP  = OFF_HSQ   + 1310720;        // 393216
constexpr size_t OFF_HSRP  = OFF_HSWP  + 393216;         // 131072
constexpr size_t OFF_HSWR  = OFF_HSRP  + 131072;         // 393216
constexpr size_t OFF_HSRR  = OFF_HSWR  + 393216;         // 131072
constexpr size_t OFF_CS    = OFF_HSRR  + 131072;         // 163840 (during steps: flag slots)
constexpr size_t OFF_RELP  = OFF_CS    + 163840;         // 524288 (during steps: Hhi/Hlo planes)
constexpr size_t OFF_RELC  = OFF_RELP  + 524288;         // 524288
constexpr size_t OFF_RELW  = OFF_RELC  + 524288;         // 524288
constexpr size_t OFF_EN    = OFF_RELW  + 524288;         // 40960
// end = OFF_EN + 40960 = 19998720 floats (~80 MB)
// XP region aliases (XP dead after k_steps):
//   QO1 +0 (1310720), ATT +1310720, QO2 +2621440,
//   Dhi +3932160 (655360 fl), Dlo +4587520,
//   RPhi +5242880, RPlo +5505024, RChi +5767168, RClo +6029312 (dead before k_m2)
//   M2hi +5242880 (1313024 fl), M2lo +6555904,
//   Y1 +7868928, Y2 +8360448, Y3 +8851968 (end 9343488 < 9437184)

__device__ inline unsigned short f2bf(float f) {
  unsigned int u = __float_as_uint(f);
  u += 0x7FFFu + ((u >> 16) & 1u);          // RNE
  return (unsigned short)(u >> 16);
}
__device__ inline float bf2f(unsigned short h) {
  return __uint_as_float(((unsigned int)h) << 16);
}
__device__ inline short8 mk8(unsigned long long a, unsigned long long b) {
  union { unsigned long long q[2]; short8 s; } u;
  u.q[0] = a; u.q[1] = b; return u.s;
}
#define ALD(p) __hip_atomic_load((p), __ATOMIC_RELAXED, __HIP_MEMORY_SCOPE_AGENT)

// ================= prep: WHB (tile16 gate-interleaved Whh bf16 hi|lo) + bias + B3T =====
// WHB layout: [dir][tile 16][row = g*16+uu (64)][hi k 0..255 | lo k 0..255]
__global__ __launch_bounds__(256) void k_prep(
    const float* __restrict__ Whh_f, const float* __restrict__ Whh_b,
    const float* __restrict__ b_f,   const float* __restrict__ b_b,
    const float* __restrict__ Wih_f, const float* __restrict__ Wih_b,
    const float* __restrict__ Wat,   const float* __restrict__ l2w,
    const float* __restrict__ c1w, const float* __restrict__ c2w, const float* __restrict__ c3w,
    unsigned short* __restrict__ WHB, float* __restrict__ B2,
    unsigned short* __restrict__ XB3T, unsigned short* __restrict__ WB3T,
    unsigned short* __restrict__ L2B3T,
    unsigned short* __restrict__ C1B3T, unsigned short* __restrict__ C2B3T,
    unsigned short* __restrict__ C3B3T, int* __restrict__ flags) {
  int idx = blockIdx.x * 256 + threadIdx.x;
  if (idx < 3072)                           // reset per-tile step flags (64B apart each)
    __hip_atomic_store(flags + idx * 16, 0, __ATOMIC_RELAXED, __HIP_MEMORY_SCOPE_AGENT);
  if (idx < 1048576) {                      // WHB
    int e = idx & 511;                      // k + 256*isLo
    int k = e & 255, isLo = e >> 8;
    int row = (idx >> 9) & 63;              // g*16+uu
    int tile = (idx >> 15) & 15;
    int d = idx >> 19;
    int g = row >> 4, uu = row & 15;
    int u = tile * 16 + uu;
    const float* Wh = d ? Whh_b : Whh_f;
    float w = Wh[(size_t)(g * 256 + u) * 256 + k];
    unsigned short hi = f2bf(w);
    WHB[idx] = isLo ? f2bf(w - bf2f(hi)) : hi;
    return;
  }
  idx -= 1048576;
  if (idx < 2048) { B2[idx] = (idx < 1024) ? b_f[idx] : b_b[idx-1024]; return; }
  idx -= 2048;
  unsigned short* dst; int n, k, K;
  float w;
  if (idx < 655360) {                       // XB3T: n<2048, Kp=320 (src K=300)
    n = idx / 320; k = idx % 320; K = 320; dst = XB3T;
    w = (k < 300) ? ((n < 1024) ? Wih_f[(size_t)n*300 + k] : Wih_b[(size_t)(n-1024)*300 + k]) : 0.f;
  } else if ((idx -= 655360) < 262144) {    // WB3T: B[k][n] = Wat[k][n]
    n = idx >> 9; k = idx & 511; K = 512; dst = WB3T;
    w = Wat[(size_t)k*512 + n];
  } else if ((idx -= 262144) < 262144) {    // L2B3T: B[k][n] = l2w[n][k]
    n = idx >> 9; k = idx & 511; K = 512; dst = L2B3T;
    w = l2w[(size_t)n*512 + k];
  } else if ((idx -= 262144) < 196608) {    // C1B3T (n pad 192)
    n = idx >> 10; k = idx & 1023; K = 1024; dst = C1B3T;
    w = (n < 150) ? c1w[(size_t)n*1024 + k] : 0.f;
  } else if ((idx -= 196608) < 589824) {    // C2B3T
    n = idx / 3072; k = idx % 3072; K = 3072; dst = C2B3T;
    int kw = k >> 10, c = k & 1023;
    w = (n < 150) ? c2w[((size_t)n*1024 + c)*3 + kw] : 0.f;
  } else if ((idx -= 589824) < 983040) {    // C3B3T
    n = idx / 5120; k = idx % 5120; K = 5120; dst = C3B3T;
    int kw = k >> 10, c = k & 1023;
    w = (n < 150) ? c3w[((size_t)n*1024 + c)*5 + kw] : 0.f;
  } else return;
  unsigned short hi = f2bf(w);
  unsigned short lo = f2bf(w - bf2f(hi));
  size_t base = (size_t)n * (3*K);
  dst[base + k] = hi;
  dst[base + K + k] = lo;
  dst[base + 2*K + k] = hi;
}

// ================= gather embeddings -> bf16 split, K padded to 320 =================
__global__ __launch_bounds__(320) void k_gather(
    const int* __restrict__ q,  const int* __restrict__ wr, const int* __restrict__ rr,
    const int* __restrict__ wp, const int* __restrict__ rp,
    const float* __restrict__ we, const float* __restrict__ re,
    unsigned short* __restrict__ Xhi, unsigned short* __restrict__ Xlo) {
  int m = blockIdx.x, k = threadIdx.x;
  const float* emb; int row;
  if (m < 2560)      { int t=m>>6,    b=m&63; row = q [b*40+t]; emb = we; }
  else if (m < 3328) { int mm=m-2560; int t=mm>>6,b=mm&63; row = wp[b*12+t]; emb = we; }
  else if (m < 3584) { int mm=m-3328; int t=mm>>6,b=mm&63; row = rp[b*4 +t]; emb = re; }
  else if (m < 4352) { int mm=m-3584; int t=mm>>6,b=mm&63; row = wr[b*12+t]; emb = we; }
  else               { int mm=m-4352; int t=mm>>6,b=mm&63; row = rr[b*4 +t]; emb = re; }
  float v = (k < 300) ? emb[(size_t)row*300 + k] : 0.f;
  unsigned short hi = f2bf(v);
  Xhi[(size_t)m*320 + k] = hi;
  Xlo[(size_t)m*320 + k] = f2bf(v - bf2f(hi));
}

// ===== MFMA GEMM (bf16 3-split): C[M][N] = sum over 3K of Asel[m][kk] * Bt[n][k0] =====
template<bool BIAS>
__global__ __launch_bounds__(256) void k_mgemm(
    const unsigned short* __restrict__ Ahi, const unsigned short* __restrict__ Alo, int lda,
    const unsigned short* __restrict__ Bt, const float* __restrict__ bias,
    float* __restrict__ C, int N, int K) {
  __shared__ unsigned short As[64 * 40];   // rows padded to 40 ushorts (80 B)
  __shared__ unsigned short Bs[64 * 40];
  int tid = threadIdx.x;
  int wave = tid >> 6, lane = tid & 63;
  int quad = lane >> 4, l16 = lane & 15;
  int m0 = blockIdx.x << 6, n0 = blockIdx.y << 6;
  int K3 = 3 * K;
  int sr = tid >> 2;               // staging row 0..63
  int sc = (tid & 3) << 3;         // staging col 0,8,16,24
  f32x4 acc[4] = {};
  for (int k0 = 0; k0 < K3; k0 += 32) {
    int c = (k0 >= K) + (k0 >= 2*K);
    const unsigned short* Asrc = (c == 2) ? Alo : Ahi;
    int kk = k0 - c * K;
    ushort8 av = *(const ushort8*)(Asrc + (size_t)(m0 + sr) * lda + kk + sc);
    ushort8 bv = *(const ushort8*)(Bt + (size_t)(n0 + sr) * K3 + k0 + sc);
    *(ushort8*)&As[sr * 40 + sc] = av;
    *(ushort8*)&Bs[sr * 40 + sc] = bv;
    __syncthreads();
    short8 a  = *(const short8*)&As[(wave*16 + l16) * 40 + quad*8];
    short8 b0 = *(const short8*)&Bs[( 0 + l16) * 40 + quad*8];
    short8 b1 = *(const short8*)&Bs[(16 + l16) * 40 + quad*8];
    short8 b2 = *(const short8*)&Bs[(32 + l16) * 40 + quad*8];
    short8 b3 = *(const short8*)&Bs[(48 + l16) * 40 + quad*8];
    acc[0] = __builtin_amdgcn_mfma_f32_16x16x32_bf16(a, b0, acc[0], 0, 0, 0);
    acc[1] = __builtin_amdgcn_mfma_f32_16x16x32_bf16(a, b1, acc[1], 0, 0, 0);
    acc[2] = __builtin_amdgcn_mfma_f32_16x16x32_bf16(a, b2, acc[2], 0, 0, 0);
    acc[3] = __builtin_amdgcn_mfma_f32_16x16x32_bf16(a, b3, acc[3], 0, 0, 0);
    __syncthreads();
  }
  int row0 = m0 + wave * 16 + quad * 4;    // C/D: col=lane&15, row=quad*4+reg
#pragma unroll
  for (int t = 0; t < 4; t++) {
    int col = n0 + t * 16 + l16;
    float bb = BIAS ? bias[col] : 0.f;
#pragma unroll
    for (int r = 0; r < 4; r++)
      C[(size_t)(row0 + r) * N + col] = acc[t][r] + bb;
  }
}

// ===== fused conv GEMMs, split-K, atomic accumulate into zeroed Y =====
// blockIdx.z: [0,4) conv1 split, [4,12) conv2 split, [12,20) conv3 split
__global__ __launch_bounds__(256) void k_cgemm(
    const unsigned short* __restrict__ Ahi, const unsigned short* __restrict__ Alo,
    const unsigned short* __restrict__ B1, const unsigned short* __restrict__ B2c,
    const unsigned short* __restrict__ B3,
    float* __restrict__ Y1, float* __restrict__ Y2, float* __restrict__ Y3) {
  __shared__ unsigned short As[64 * 40];
  __shared__ unsigned short Bs[64 * 40];
  int z = blockIdx.z;
  const unsigned short* Bt; float* Y; int K, sidx, chunk;
  if (z < 4)       { Bt = B1;  Y = Y1; K = 1024; sidx = z;      chunk = 768;  }
  else if (z < 12) { Bt = B2c; Y = Y2; K = 3072; sidx = z - 4;  chunk = 1152; }
  else             { Bt = B3;  Y = Y3; K = 5120; sidx = z - 12; chunk = 1920; }
  int K3 = 3 * K;
  int ks = sidx * chunk, ke = ks + chunk;
  int tid = threadIdx.x;
  int wave = tid >> 6, lane = tid & 63;
  int quad = lane >> 4, l16 = lane & 15;
  int m0 = blockIdx.x << 6, n0 = blockIdx.y << 6;
  int sr = tid >> 2;
  int sc = (tid & 3) << 3;
  f32x4 acc[4] = {};
  for (int k0 = ks; k0 < ke; k0 += 32) {
    int c = (k0 >= K) + (k0 >= 2*K);
    const unsigned short* Asrc = (c == 2) ? Alo : Ahi;
    int kk = k0 - c * K;
    ushort8 av = *(const ushort8*)(Asrc + (size_t)(m0 + sr) * 1024 + kk + sc);
    ushort8 bv = *(const ushort8*)(Bt + (size_t)(n0 + sr) * K3 + k0 + sc);
    *(ushort8*)&As[sr * 40 + sc] = av;
    *(ushort8*)&Bs[sr * 40 + sc] = bv;
    __syncthreads();
    short8 a  = *(const short8*)&As[(wave*16 + l16) * 40 + quad*8];
    short8 b0 = *(const short8*)&Bs[( 0 + l16) * 40 + quad*8];
    short8 b1 = *(const short8*)&Bs[(16 + l16) * 40 + quad*8];
    short8 b2 = *(const short8*)&Bs[(32 + l16) * 40 + quad*8];
    short8 b3 = *(const short8*)&Bs[(48 + l16) * 40 + quad*8];
    acc[0] = __builtin_amdgcn_mfma_f32_16x16x32_bf16(a, b0, acc[0], 0, 0, 0);
    acc[1] = __builtin_amdgcn_mfma_f32_16x16x32_bf16(a, b1, acc[1], 0, 0, 0);
    acc[2] = __builtin_amdgcn_mfma_f32_16x16x32_bf16(a, b2, acc[2], 0, 0, 0);
    acc[3] = __builtin_amdgcn_mfma_f32_16x16x32_bf16(a, b3, acc[3], 0, 0, 0);
    __syncthreads();
  }
  int row0 = m0 + wave * 16 + quad * 4;
#pragma unroll
  for (int t = 0; t < 4; t++) {
    int col = n0 + t * 16 + l16;
#pragma unroll
    for (int r = 0; r < 4; r++)
      atomicAdd(&Y[(size_t)(row0 + r) * 192 + col], acc[t][r]);
  }
}

// ================= zero a float region (Y partial-sum init) =================
__global__ __launch_bounds__(256) void k_zero(float* __restrict__ p, int n4) {
  int idx = blockIdx.x * 256 + threadIdx.x;
  if (idx < n4) *(float4*)(p + (size_t)idx * 4) = make_float4(0.f, 0.f, 0.f, 0.f);
}

// ========== persistent recurrent kernel v4: regs-only + parallel flag barrier ==========
// 128 blocks; chain = bid&7 (0..5 active), tile = bid>>3 (0..15).
// Per block: M=64 batches x N=64 (4 gates x 16 u) x K=256, bf16x3.
// Weights (B-frags, step-invariant) live in registers: Bh[4][8] + Bl[4][8] short8.
// h exchanged via TWO sc1 ushort planes (hi,lo); 16B load IS an A-frag directly.
// Sync: per-(chain,parity,tile) flag word (own 64B line, monotonic value cs+1).
//   writer: sc1 h-stores -> __syncthreads (drains vmcnt) -> ONE plain sc1 flag store.
//   reader: lanes tid<16 poll the 16 flags IN PARALLEL -> __syncthreads.
// No RMW atomics, no shared lines across chains -> no serialization at L3.
__global__ __launch_bounds__(256, 1) void k_steps(
    const unsigned short* __restrict__ WHB, const float* __restrict__ XP,
    float* __restrict__ hsQ, float* __restrict__ hsWp, float* __restrict__ hsRp,
    float* __restrict__ hsWr, float* __restrict__ hsRr,
    unsigned short* __restrict__ Hhi, unsigned short* __restrict__ Hlo,
    int* __restrict__ flags) {
  int bid = blockIdx.x;
  int chain = bid & 7;
  if (chain >= 6) return;                // 2 of 8 xcd-slots idle
  int tile = bid >> 3;                   // 0..15
  int dir = chain & 1, fam = chain >> 1;
  int tid = threadIdx.x;
  int wave = tid >> 6, lane = tid & 63;
  int quad = lane >> 4, l16 = lane & 15;
  int u0 = tile << 4;

  // ---- load weight B-fragments into registers once (step-invariant) ----
  const unsigned short* wsrc = WHB + (((size_t)dir * 16 + tile) << 15);   // 64 rows x 512
  short8 Bh[4][8], Bl[4][8];
#pragma unroll
  for (int nf = 0; nf < 4; nf++)
#pragma unroll
    for (int j = 0; j < 8; j++) {
      const unsigned short* wr = wsrc + (nf * 16 + l16) * 512 + j * 32 + quad * 8;
      Bh[nf][j] = *(const short8*)(wr);
      Bl[nf][j] = *(const short8*)(wr + 256);
    }

  int nsteps = (fam == 0) ? 40 : 16;
  float creg[4] = {0.f, 0.f, 0.f, 0.f};
  int row64 = (wave * 16 + l16) * 64 + quad * 2;   // u64 index of this lane's A-frag row base

  for (int cs = 0; cs < nsteps; cs++) {
    // ---- phase params + XP prefetch (issued before the flag wait) ----
    int t, T, seg; float* hsb;
    if (fam == 0)     { t = cs;      T = 40; seg = 0;                         hsb = hsQ + (size_t)dir * 40 * BH; }
    else if (cs < 12) { t = cs;      T = 12; seg = (fam == 1) ? 2560 : 3584;  hsb = ((fam == 1) ? hsWp : hsWr) + (size_t)dir * 12 * BH; }
    else              { t = cs - 12; T = 4;  seg = (fam == 1) ? 3328 : 4352;  hsb = ((fam == 1) ? hsRp : hsRr) + (size_t)dir * 4 * BH; }
    int t_in = dir ? (T - 1 - t) : t;
    int u = u0 + l16;
    const float* xb = XP + (size_t)(seg + t_in * 64) * 2048 + dir * 1024 + u;
    float xi[4], xf[4], xg[4], xo[4];
#pragma unroll
    for (int r = 0; r < 4; r++) {
      const float* xr = xb + (size_t)(wave * 16 + quad * 4 + r) * 2048;
      xi[r] = xr[0]; xf[r] = xr[256]; xg[r] = xr[512]; xo[r] = xr[768];
    }

    f32x4 acc[4] = {};
    if (cs > 0) {
      // ---- parallel flag wait: lane i watches tile i's flag (16 separate lines) ----
      if (tid < 16) {
        const int* fp = flags + ((((chain << 1) | ((cs - 1) & 1)) * 16 + tid) << 4);
        while (__hip_atomic_load(fp, __ATOMIC_RELAXED, __HIP_MEMORY_SCOPE_AGENT) < cs)
          __builtin_amdgcn_s_sleep(2);
      }
      __syncthreads();
      // ---- coherent h load, direct to A-frags (hi plane + lo plane) ----
      size_t slotq = (size_t)(chain * 2 + ((cs - 1) & 1)) * 4096;   // u64 units (16384 ush)
      const unsigned long long* ph = (const unsigned long long*)Hhi + slotq + row64;
      const unsigned long long* pl = (const unsigned long long*)Hlo + slotq + row64;
      unsigned long long rv[32];
#pragma unroll
      for (int j = 0; j < 8; j++) { rv[2*j] = ALD(ph + 8*j); rv[2*j+1] = ALD(ph + 8*j + 1); }
#pragma unroll
      for (int j = 0; j < 8; j++) { rv[16+2*j] = ALD(pl + 8*j); rv[16+2*j+1] = ALD(pl + 8*j + 1); }
      short8 ah[8], al[8];
#pragma unroll
      for (int j = 0; j < 8; j++) { ah[j] = mk8(rv[2*j], rv[2*j+1]); al[j] = mk8(rv[16+2*j], rv[16+2*j+1]); }
      // ---- bf16x3, all operands in registers ----
#pragma unroll
      for (int j = 0; j < 8; j++) {
        acc[0] = __builtin_amdgcn_mfma_f32_16x16x32_bf16(ah[j], Bh[0][j], acc[0], 0, 0, 0);
        acc[1] = __builtin_amdgcn_mfma_f32_16x16x32_bf16(ah[j], Bh[1][j], acc[1], 0, 0, 0);
        acc[2] = __builtin_amdgcn_mfma_f32_16x16x32_bf16(ah[j], Bh[2][j], acc[2], 0, 0, 0);
        acc[3] = __builtin_amdgcn_mfma_f32_16x16x32_bf16(ah[j], Bh[3][j], acc[3], 0, 0, 0);
      }
#pragma unroll
      for (int j = 0; j < 8; j++) {
        acc[0] = __builtin_amdgcn_mfma_f32_16x16x32_bf16(ah[j], Bl[0][j], acc[0], 0, 0, 0);
        acc[1] = __builtin_amdgcn_mfma_f32_16x16x32_bf16(ah[j], Bl[1][j], acc[1], 0, 0, 0);
        acc[2] = __builtin_amdgcn_mfma_f32_16x16x32_bf16(ah[j], Bl[2][j], acc[2], 0, 0, 0);
        acc[3] = __builtin_amdgcn_mfma_f32_16x16x32_bf16(ah[j], Bl[3][j], acc[3], 0, 0, 0);
      }
#pragma unroll
      for (int j = 0; j < 8; j++) {
        acc[0] = __builtin_amdgcn_mfma_f32_16x16x32_bf16(al[j], Bh[0][j], acc[0], 0, 0, 0);
        acc[1] = __builtin_amdgcn_mfma_f32_16x16x32_bf16(al[j], Bh[1][j], acc[1], 0, 0, 0);
        acc[2] = __builtin_amdgcn_mfma_f32_16x16x32_bf16(al[j], Bh[2][j], acc[2], 0, 0, 0);
        acc[3] = __builtin_amdgcn_mfma_f32_16x16x32_bf16(al[j], Bh[3][j], acc[3], 0, 0, 0);
      }
    }
    // ---- gates + state update (acc frag nf = gate; row = batch; col = u) ----
    float hnv[4];
#pragma unroll
    for (int r = 0; r < 4; r++) {
      float zi = acc[0][r] + xi[r];
      float zf = acc[1][r] + xf[r];
      float zg = acc[2][r] + xg[r];
      float zo = acc[3][r] + xo[r];
      float gi = 1.f / (1.f + expf(-zi));
      float gf = 1.f / (1.f + expf(-zf));
      float go = 1.f / (1.f + expf(-zo));
      float gg = tanhf(zg);
      float cn = gf * creg[r] + gi * gg;
      hnv[r] = go * tanhf(cn);
      creg[r] = cn;
    }
    // sc1 plane stores first (long ack overlaps the fp32 stores below)
    size_t oslot = (size_t)(chain * 2 + (cs & 1)) << 14;
    unsigned short* oh = Hhi + oslot;
    unsigned short* ol = Hlo + oslot;
#pragma unroll
    for (int r = 0; r < 4; r++) {
      int b = wave * 16 + quad * 4 + r;
      unsigned short h16 = f2bf(hnv[r]);
      unsigned short l16v = f2bf(hnv[r] - bf2f(h16));
      unsigned int pk = (unsigned int)h16 | ((unsigned int)l16v << 16);
      unsigned int pw = (unsigned int)__shfl_xor((int)pk, 1, 64);   // partner lane (u^1)
      if ((lane & 1) == 0) {
        unsigned int hw = (pk & 0xFFFFu) | (pw << 16);              // hi(u), hi(u+1)
        unsigned int lw = (pk >> 16) | (pw & 0xFFFF0000u);          // lo(u), lo(u+1)
        __hip_atomic_store((unsigned int*)(oh + b * 256 + u), hw,
                           __ATOMIC_RELAXED, __HIP_MEMORY_SCOPE_AGENT);
        __hip_atomic_store((unsigned int*)(ol + b * 256 + u), lw,
                           __ATOMIC_RELAXED, __HIP_MEMORY_SCOPE_AGENT);
      }
    }
    float* hout = hsb + (size_t)t * BH + u;
#pragma unroll
    for (int r = 0; r < 4; r++) {
      int b = wave * 16 + quad * 4 + r;
      hout[(size_t)b * 256] = hnv[r];
    }
    if (cs + 1 < nsteps) {
      __syncthreads();                  // drains vmcnt(0): sc1 stores ack'd at coherence point
      if (tid == 0)
        __hip_atomic_store(flags + ((((chain << 1) | (cs & 1)) * 16 + tile) << 4), cs + 1,
                           __ATOMIC_RELAXED, __HIP_MEMORY_SCOPE_AGENT);
    }
  }
}

// ================= question_out as [b][s][h] =================
__global__ __launch_bounds__(256) void k_qo1(const float* __restrict__ hsQ, float* __restrict__ QT) {
  int idx = blockIdx.x * 256 + threadIdx.x;
  if (idx >= 64*40*512) return;
  int h = idx & 511; int t2 = idx >> 9; int s = t2 % 40; int b = t2 / 40;
  float v;
  if (h < 256) v = hsQ[(size_t)s * BH + b*256 + h];
  else         v = hsQ[(size_t)40 * BH + (size_t)(39 - s) * BH + b*256 + (h - 256)];
  QT[idx] = v;
}

// ================= relation tensors [b][r][h] fp32 + bf16-split, both calls ==============
__global__ __launch_bounds__(256) void k_rel(
    const float* __restrict__ hsWp, const float* __restrict__ hsRp,
    const float* __restrict__ hsWr, const float* __restrict__ hsRr,
    float* __restrict__ RELP, float* __restrict__ RELC,
    unsigned short* __restrict__ RPhi, unsigned short* __restrict__ RPlo,
    unsigned short* __restrict__ RChi, unsigned short* __restrict__ RClo) {
  int idx0 = blockIdx.x * 256 + threadIdx.x;
  if (idx0 >= 2*64*16*512) return;
  int call = idx0 >= 64*16*512;
  int idx = idx0 - call * 64*16*512;
  int h = idx & 511; int t2 = idx >> 9; int r = t2 & 15; int b = t2 >> 4;
  const float* hsW = call ? hsWr : hsWp;
  const float* hsR = call ? hsRr : hsRp;
  float v;
  if (r < 4) {
    if (h < 256) v = hsR[(size_t)r * BH + b*256 + h];
    else         v = hsR[(size_t)4 * BH + (size_t)(3 - r) * BH + b*256 + (h - 256)];
  } else {
    int t = r - 4;
    if (h < 256) v = hsW[(size_t)t * BH + b*256 + h];
    else         v = hsW[(size_t)12 * BH + (size_t)(11 - t) * BH + b*256 + (h - 256)];
  }
  unsigned short hi = f2bf(v);
  unsigned short lo = f2bf(v - bf2f(hi));
  if (call) { RELC[idx] = v; RChi[idx] = hi; RClo[idx] = lo; }
  else      { RELP[idx] = v; RPhi[idx] = hi; RPlo[idx] = lo; }
}

// ================= energy[b][r][s] =================
__global__ __launch_bounds__(256) void k_energy(
    const float* __restrict__ relW, const float* __restrict__ QT, float* __restrict__ EN) {
  int idx = blockIdx.x * 256 + threadIdx.x;
  if (idx >= 64*16*40) return;
  int s = idx % 40; int t = idx / 40; int r = t & 15; int b = t >> 4;
  const float* rw = relW + (size_t)(b*16 + r) * 512;
  const float* qv = QT   + (size_t)(b*40 + s) * 512;
  float acc = 0.f;
#pragma unroll 4
  for (int k = 0; k < 512; k += 4) {
    float4 a = *(const float4*)(rw + k);
    float4 c = *(const float4*)(qv + k);
    acc += a.x*c.x + a.y*c.y + a.z*c.z + a.w*c.w;
  }
  EN[idx] = acc;
}

// ================= softmax over 640 per b =================
__global__ __launch_bounds__(256) void k_softmax(float* __restrict__ EN) {
  int b = blockIdx.x; int tid = threadIdx.x;
  float* e = EN + b * 640;
  float v0 = e[tid] * 0.25f, v1 = e[tid + 256] * 0.25f;
  float v2 = (tid < 128) ? e[tid + 512] * 0.25f : NEG_INF;
  __shared__ float sh[256];
  sh[tid] = fmaxf(v0, fmaxf(v1, v2));
  __syncthreads();
  for (int st = 128; st > 0; st >>= 1) { if (tid < st) sh[tid] = fmaxf(sh[tid], sh[tid+st]); __syncthreads(); }
  float m = sh[0];
  __syncthreads();
  float e0 = expf(v0 - m), e1 = expf(v1 - m);
  float e2 = (tid < 128) ? expf(v2 - m) : 0.f;
  sh[tid] = e0 + e1 + e2;
  __syncthreads();
  for (int st = 128; st > 0; st >>= 1) { if (tid < st) sh[tid] += sh[tid+st]; __syncthreads(); }
  float inv = 1.f / sh[0];
  e[tid] = e0 * inv; e[tid + 256] = e1 * inv;
  if (tid < 128) e[tid + 512] = e2 * inv;
}

// ================= atten[b][s][h] =================
__global__ __launch_bounds__(256) void k_atten(
    const float* __restrict__ AL, const float* __restrict__ REL, float* __restrict__ ATT) {
  int idx = blockIdx.x * 256 + threadIdx.x;
  if (idx >= 64*40*512) return;
  int h = idx & 511; int t2 = idx >> 9; int s = t2 % 40; int b = t2 / 40;
  const float* al = AL + b * 640 + s;
  const float* rl = REL + (size_t)b * 16 * 512 + h;
  float acc = 0.f;
#pragma unroll
  for (int r = 0; r < 16; r++) acc += al[r*40] * rl[r*512];
  ATT[idx] = acc;
}

// ================= (QT - ATT) -> bf16 split =================
__global__ __launch_bounds__(256) void k_sub(
    const float* __restrict__ QT, const float* __restrict__ ATT,
    unsigned short* __restrict__ Dhi, unsigned short* __restrict__ Dlo) {
  int idx = blockIdx.x * 256 + threadIdx.x;
  if (idx >= 64*40*512) return;
  float v = QT[idx] - ATT[idx];
  unsigned short hi = f2bf(v);
  Dhi[idx] = hi; Dlo[idx] = f2bf(v - bf2f(hi));
}

// ================= pack M2[m][c] bf16-split, with zero tail pad =================
__global__ __launch_bounds__(256) void k_m2(
    const float* __restrict__ QO2, const float* __restrict__ ATT,
    unsigned short* __restrict__ M2hi, unsigned short* __restrict__ M2lo) {
  int idx = blockIdx.x * 256 + threadIdx.x;
  if (idx >= 2626048) return;
  float v = 0.f;
  if (idx < 2621440) {
    int c = idx & 1023; int m = idx >> 10;
    v = (c < 512) ? QO2[(size_t)m*512 + c] : ATT[(size_t)m*512 + (c - 512)];
  }
  unsigned short hi = f2bf(v);
  M2hi[idx] = hi; M2lo[idx] = f2bf(v - bf2f(hi));
}

// ================= pool(bias+relu+max over l) + score =================
__global__ __launch_bounds__(256) void k_pool(
    const float* __restrict__ Y1, const float* __restrict__ Y2, const float* __restrict__ Y3,
    const float* __restrict__ b1, const float* __restrict__ b2, const float* __restrict__ b3,
    const float* __restrict__ lw, float* __restrict__ out) {
  int b = blockIdx.x, o = threadIdx.x;
  float hv = 0.f;
  if (o < 150) {
    const float* y1 = Y1 + (size_t)b*40*192 + o;
    const float* y2 = Y2 + (size_t)b*40*192 + o;
    const float* y3 = Y3 + (size_t)b*40*192 + o;
    float m1 = NEG_INF, m2 = NEG_INF, m3 = NEG_INF;
#pragma unroll 4
    for (int l = 0; l < 40; l++) m1 = fmaxf(m1, y1[l*192]);
#pragma unroll 2
    for (int l = 0; l < 38; l++) m2 = fmaxf(m2, y2[l*192]);
#pragma unroll 2
    for (int l = 0; l < 36; l++) m3 = fmaxf(m3, y3[l*192]);
    float h = fmaxf(fmaxf(m1 + b1[o], m2 + b2[o]), m3 + b3[o]);
    hv = fmaxf(h, 0.f) * lw[o];
  }
  __shared__ float sh[256];
  sh[threadIdx.x] = hv;
  __syncthreads();
  for (int st = 128; st > 0; st >>= 1) { if (threadIdx.x < st) sh[threadIdx.x] += sh[threadIdx.x+st]; __syncthreads(); }
  if (threadIdx.x == 0) out[b] = sh[0];
}

// ================= host =================
extern "C" void kernel_launch(void* const* d_in, const int* in_sizes, int n_in,
                              void* d_out, int out_size, void* d_ws, size_t ws_size,
                              hipStream_t stream) {
  const int*   q    = (const int*)d_in[0];
  const int*   wrel = (const int*)d_in[1];
  const int*   rrel = (const int*)d_in[2];
  const int*   wprv = (const int*)d_in[3];
  const int*   rprv = (const int*)d_in[4];
  const float* we   = (const float*)d_in[5];
  const float* re   = (const float*)d_in[6];
  const float* Wih_f= (const float*)d_in[7];
  const float* Whh_f= (const float*)d_in[8];
  const float* b_f  = (const float*)d_in[9];
  const float* Wih_b= (const float*)d_in[10];
  const float* Whh_b= (const float*)d_in[11];
  const float* b_b  = (const float*)d_in[12];
  const float* W    = (const float*)d_in[13];
  const float* c1w  = (const float*)d_in[14];
  const float* c1b  = (const float*)d_in[15];
  const float* c2w  = (const float*)d_in[16];
  const float* c2b  = (const float*)d_in[17];
  const float* c3w  = (const float*)d_in[18];
  const float* c3b  = (const float*)d_in[19];
  const float* lw   = (const float*)d_in[20];
  const float* l2w  = (const float*)d_in[21];
  const float* l2b  = (const float*)d_in[22];
  float* out = (float*)d_out;
  float* ws  = (float*)d_ws;

  unsigned short* WHB = (unsigned short*)(ws + OFF_WQ);   // 1048576 ush (exact fit)
  float* B2   = ws + OFF_B2;
  unsigned short* XB3T  = (unsigned short*)(ws + OFF_XB3T);
  unsigned short* WB3T  = (unsigned short*)(ws + OFF_WB3T);
  unsigned short* L2B3T = (unsigned short*)(ws + OFF_L2B3T);
  unsigned short* C1B3T = (unsigned short*)(ws + OFF_C1B3T);
  unsigned short* C2B3T = (unsigned short*)(ws + OFF_C2B3T);
  unsigned short* C3B3T = (unsigned short*)(ws + OFF_C3B3T);
  unsigned short* Xhi   = (unsigned short*)(ws + OFF_XHI);
  unsigned short* Xlo   = (unsigned short*)(ws + OFF_XLO);
  float* XP   = ws + OFF_XP;
  float* HSQ  = ws + OFF_HSQ;
  float* HSWP = ws + OFF_HSWP;
  float* HSRP = ws + OFF_HSRP;
  float* HSWR = ws + OFF_HSWR;
  float* HSRR = ws + OFF_HSRR;
  int*   flags = (int*)(ws + OFF_CS);                     // CS region repurposed (3072x16 ints)
  float* RELP = ws + OFF_RELP;
  float* RELC = ws + OFF_RELC;
  float* RELW = ws + OFF_RELW;
  float* EN   = ws + OFF_EN;
  // During the step loop, the RELP region holds the h planes:
  // Hhi [6 chain][2 parity][64 b][256 u] ush = 196608 ush; Hlo same after = 393216 ush total
  // = 196608 fl < 524288 fl.
  unsigned short* Hhi = (unsigned short*)(ws + OFF_RELP);
  unsigned short* Hlo = Hhi + 196608;
  // XP-region aliases (XP dead after k_steps)
  float* QO1  = XP;
  float* ATT  = XP + 1310720;
  float* QO2  = XP + 2621440;
  unsigned short* Dhi  = (unsigned short*)(XP + 3932160);
  unsigned short* Dlo  = (unsigned short*)(XP + 4587520);
  unsigned short* RPhi = (unsigned short*)(XP + 5242880);
  unsigned short* RPlo = (unsigned short*)(XP + 5505024);
  unsigned short* RChi = (unsigned short*)(XP + 5767168);
  unsigned short* RClo = (unsigned short*)(XP + 6029312);
  unsigned short* M2hi = (unsigned short*)(XP + 5242880);   // overwrites RP/RC (dead by then)
  unsigned short* M2lo = (unsigned short*)(XP + 6555904);
  float* Y1   = XP + 7868928;
  float* Y2   = XP + 8360448;
  float* Y3   = XP + 8851968;

  k_prep<<<15624, 256, 0, stream>>>(Whh_f, Whh_b, b_f, b_b, Wih_f, Wih_b, W, l2w,
                                    c1w, c2w, c3w,
                                    WHB, B2, XB3T, WB3T, L2B3T, C1B3T, C2B3T, C3B3T, flags);
  k_gather<<<NTOK, 320, 0, stream>>>(q, wrel, rrel, wprv, rprv, we, re, Xhi, Xlo);
  { dim3 g(72, 32); k_mgemm<true><<<g, 256, 0, stream>>>(Xhi, Xlo, 320, XB3T, B2, XP, 2048, 320); }

  // ---- all 40 recurrent steps in one persistent kernel (regs-only, flag barrier) ----
  k_steps<<<128, 256, 0, stream>>>(WHB, XP, HSQ, HSWP, HSRP, HSWR, HSRR, Hhi, Hlo, flags);

  k_qo1<<<5120, 256, 0, stream>>>(HSQ, QO1);
  k_rel<<<4096, 256, 0, stream>>>(HSWP, HSRP, HSWR, HSRR, RELP, RELC, RPhi, RPlo, RChi, RClo);

  // ---- attention (previous hop) ----
  { dim3 g(16, 8); k_mgemm<false><<<g, 256, 0, stream>>>(RPhi, RPlo, 512, WB3T, nullptr, RELW, 512, 512); }
  k_energy<<<160, 256, 0, stream>>>(RELW, QO1, EN);
  k_softmax<<<64, 256, 0, stream>>>(EN);
  k_atten<<<5120, 256, 0, stream>>>(EN, RELP, ATT);
  k_sub<<<5120, 256, 0, stream>>>(QO1, ATT, Dhi, Dlo);
  { dim3 g(40, 8); k_mgemm<true><<<g, 256, 0, stream>>>(Dhi, Dlo, 512, L2B3T, l2b, QO2, 512, 512); }

  // ---- attention (current relation) ----
  { dim3 g(16, 8); k_mgemm<false><<<g, 256, 0, stream>>>(RChi, RClo, 512, WB3T, nullptr, RELW, 512, 512); }
  k_energy<<<160, 256, 0, stream>>>(RELW, QO2, EN);
  k_softmax<<<64, 256, 0, stream>>>(EN);
  k_atten<<<5120, 256, 0, stream>>>(EN, RELC, ATT);

  // ---- convs: fused split-K MFMA GEMM, atomic accumulate into zeroed Y ----
  k_m2<<<10258, 256, 0, stream>>>(QO2, ATT, M2hi, M2lo);
  k_zero<<<1440, 256, 0, stream>>>(Y1, 368640);   // zero Y1..Y3 (contiguous 1474560 fl)
  { dim3 g(40, 3, 20); k_cgemm<<<g, 256, 0, stream>>>(M2hi, M2lo, C1B3T, C2B3T, C3B3T, Y1, Y2, Y3); }
  k_pool<<<64, 256, 0, stream>>>(Y1, Y2, Y3, c1b, c2b, c3b, lw, out);
}

// Round 7
// 687.839 us; speedup vs baseline: 1.1483x; 1.1415x over previous
//
#include <hip/hip_runtime.h>
#include <math.h>

#define NEG_INF (-3.402823466e+38f)

typedef __attribute__((ext_vector_type(8))) short short8;
typedef __attribute__((ext_vector_type(8))) unsigned short ushort8;
typedef __attribute__((ext_vector_type(4))) float f32x4;

// ---- dims ----
constexpr int NTOK = 4608;              // 2560 Q + 768 Wp + 256 Rp + 768 Wr + 256 Rr
constexpr int BH = 64 * 256;            // one (b,u) plane

// ---- ws offsets (floats); ushort arrays use 2 elems per float slot ----
constexpr size_t OFF_WQ    = 0;                          // 524288 fl (= WHB 1048576 ush)
constexpr size_t OFF_B2    = OFF_WQ    + 524288;         // 2048
constexpr size_t OFF_XB3T  = OFF_B2    + 2048;           // 2048*960 us  = 983040 fl (k_steps: HxB)
constexpr size_t OFF_WB3T  = OFF_XB3T  + 983040;         // 512*1536 us  = 393216 fl
constexpr size_t OFF_L2B3T = OFF_WB3T  + 393216;         // 393216 fl
constexpr size_t OFF_C1B3T = OFF_L2B3T + 393216;         // 192*3072 us  = 294912 fl
constexpr size_t OFF_C2B3T = OFF_C1B3T + 294912;         // 192*9216 us  = 884736 fl
constexpr size_t OFF_C3B3T = OFF_C2B3T + 884736;         // 192*15360 us = 1474560 fl
constexpr size_t OFF_XHI   = OFF_C3B3T + 1474560;        // 4608*320 us  = 737280 fl
constexpr size_t OFF_XLO   = OFF_XHI   + 737280;
constexpr size_t OFF_XP    = OFF_XLO   + 737280;         // 4608*2048 fp32 = 9437184
constexpr size_t OFF_HSQ   = OFF_XP    + 9437184;        // 1310720
constexpr size_t OFF_HSWP  = OFF_HSQ   + 1310720;        // 393216
constexpr size_t OFF_HSRP  = OFF_HSWP  + 393216;         // 131072
constexpr size_t OFF_HSWR  = OFF_HSRP  + 131072;         // 393216
constexpr size_t OFF_HSRR  = OFF_HSWR  + 393216;         // 131072
constexpr size_t OFF_CS    = OFF_HSRR  + 131072;         // 163840 (steps: flags + det)
constexpr size_t OFF_RELP  = OFF_CS    + 163840;         // 524288 (steps: HxA slots 0..95 ...)
constexpr size_t OFF_RELC  = OFF_RELP  + 524288;         // 524288 (... spans RELP+RELC+RELW)
constexpr size_t OFF_RELW  = OFF_RELC  + 524288;         // 524288
constexpr size_t OFF_EN    = OFF_RELW  + 524288;         // 40960
// end = OFF_EN + 40960 = 19998720 floats (~80 MB)
// During k_steps: HxA = RELP..RELW (96 slots x 16384 fl), HxB = XB3T (48 slots).
// Both regions are dead during the step loop (XB3T consumed by first k_mgemm;
// REL* produced after k_steps).
// XP region aliases (XP dead after k_steps):
//   QO1 +0 (1310720), ATT +1310720, QO2 +2621440,
//   Dhi +3932160 (655360 fl), Dlo +4587520,
//   RPhi +5242880, RPlo +5505024, RChi +5767168, RClo +6029312 (dead before k_m2)
//   M2hi +5242880 (1313024 fl), M2lo +6555904,
//   Y1 +7868928, Y2 +8360448, Y3 +8851968 (end 9343488 < 9437184)

__device__ inline unsigned short f2bf(float f) {
  unsigned int u = __float_as_uint(f);
  u += 0x7FFFu + ((u >> 16) & 1u);          // RNE
  return (unsigned short)(u >> 16);
}
__device__ inline float bf2f(unsigned short h) {
  return __uint_as_float(((unsigned int)h) << 16);
}
__device__ inline short8 mk8(unsigned long long a, unsigned long long b) {
  union { unsigned long long q[2]; short8 s; } u;
  u.q[0] = a; u.q[1] = b; return u.s;
}
#define ALD(p) __hip_atomic_load((p), __ATOMIC_RELAXED, __HIP_MEMORY_SCOPE_AGENT)
#define AST(p, v) __hip_atomic_store((p), (v), __ATOMIC_RELAXED, __HIP_MEMORY_SCOPE_AGENT)

// ================= prep: WHB (tile16 gate-interleaved Whh bf16 hi|lo) + bias + B3T =====
// WHB layout: [dir][tile 16][row = g*16+uu (64)][hi k 0..255 | lo k 0..255]
__global__ __launch_bounds__(256) void k_prep(
    const float* __restrict__ Whh_f, const float* __restrict__ Whh_b,
    const float* __restrict__ b_f,   const float* __restrict__ b_b,
    const float* __restrict__ Wih_f, const float* __restrict__ Wih_b,
    const float* __restrict__ Wat,   const float* __restrict__ l2w,
    const float* __restrict__ c1w, const float* __restrict__ c2w, const float* __restrict__ c3w,
    unsigned short* __restrict__ WHB, float* __restrict__ B2,
    unsigned short* __restrict__ XB3T, unsigned short* __restrict__ WB3T,
    unsigned short* __restrict__ L2B3T,
    unsigned short* __restrict__ C1B3T, unsigned short* __restrict__ C2B3T,
    unsigned short* __restrict__ C3B3T, int* __restrict__ flags) {
  int idx = blockIdx.x * 256 + threadIdx.x;
  if (idx < 3072)                           // reset per-slot step flags (64B apart each)
    AST(flags + idx * 16, 0);
  else if (idx < 3200)                      // reset det slots (det = flags + 49152 ints)
    AST(flags + 49152 + (idx - 3072) * 16, 0);
  if (idx < 1048576) {                      // WHB
    int e = idx & 511;                      // k + 256*isLo
    int k = e & 255, isLo = e >> 8;
    int row = (idx >> 9) & 63;              // g*16+uu
    int tile = (idx >> 15) & 15;
    int d = idx >> 19;
    int g = row >> 4, uu = row & 15;
    int u = tile * 16 + uu;
    const float* Wh = d ? Whh_b : Whh_f;
    float w = Wh[(size_t)(g * 256 + u) * 256 + k];
    unsigned short hi = f2bf(w);
    WHB[idx] = isLo ? f2bf(w - bf2f(hi)) : hi;
    return;
  }
  idx -= 1048576;
  if (idx < 2048) { B2[idx] = (idx < 1024) ? b_f[idx] : b_b[idx-1024]; return; }
  idx -= 2048;
  unsigned short* dst; int n, k, K;
  float w;
  if (idx < 655360) {                       // XB3T: n<2048, Kp=320 (src K=300)
    n = idx / 320; k = idx % 320; K = 320; dst = XB3T;
    w = (k < 300) ? ((n < 1024) ? Wih_f[(size_t)n*300 + k] : Wih_b[(size_t)(n-1024)*300 + k]) : 0.f;
  } else if ((idx -= 655360) < 262144) {    // WB3T: B[k][n] = Wat[k][n]
    n = idx >> 9; k = idx & 511; K = 512; dst = WB3T;
    w = Wat[(size_t)k*512 + n];
  } else if ((idx -= 262144) < 262144) {    // L2B3T: B[k][n] = l2w[n][k]
    n = idx >> 9; k = idx & 511; K = 512; dst = L2B3T;
    w = l2w[(size_t)n*512 + k];
  } else if ((idx -= 262144) < 196608) {    // C1B3T (n pad 192)
    n = idx >> 10; k = idx & 1023; K = 1024; dst = C1B3T;
    w = (n < 150) ? c1w[(size_t)n*1024 + k] : 0.f;
  } else if ((idx -= 196608) < 589824) {    // C2B3T
    n = idx / 3072; k = idx % 3072; K = 3072; dst = C2B3T;
    int kw = k >> 10, c = k & 1023;
    w = (n < 150) ? c2w[((size_t)n*1024 + c)*3 + kw] : 0.f;
  } else if ((idx -= 589824) < 983040) {    // C3B3T
    n = idx / 5120; k = idx % 5120; K = 5120; dst = C3B3T;
    int kw = k >> 10, c = k & 1023;
    w = (n < 150) ? c3w[((size_t)n*1024 + c)*5 + kw] : 0.f;
  } else return;
  unsigned short hi = f2bf(w);
  unsigned short lo = f2bf(w - bf2f(hi));
  size_t base = (size_t)n * (3*K);
  dst[base + k] = hi;
  dst[base + K + k] = lo;
  dst[base + 2*K + k] = hi;
}

// ================= gather embeddings -> bf16 split, K padded to 320 =================
__global__ __launch_bounds__(320) void k_gather(
    const int* __restrict__ q,  const int* __restrict__ wr, const int* __restrict__ rr,
    const int* __restrict__ wp, const int* __restrict__ rp,
    const float* __restrict__ we, const float* __restrict__ re,
    unsigned short* __restrict__ Xhi, unsigned short* __restrict__ Xlo) {
  int m = blockIdx.x, k = threadIdx.x;
  const float* emb; int row;
  if (m < 2560)      { int t=m>>6,    b=m&63; row = q [b*40+t]; emb = we; }
  else if (m < 3328) { int mm=m-2560; int t=mm>>6,b=mm&63; row = wp[b*12+t]; emb = we; }
  else if (m < 3584) { int mm=m-3328; int t=mm>>6,b=mm&63; row = rp[b*4 +t]; emb = re; }
  else if (m < 4352) { int mm=m-3584; int t=mm>>6,b=mm&63; row = wr[b*12+t]; emb = we; }
  else               { int mm=m-4352; int t=mm>>6,b=mm&63; row = rr[b*4 +t]; emb = re; }
  float v = (k < 300) ? emb[(size_t)row*300 + k] : 0.f;
  unsigned short hi = f2bf(v);
  Xhi[(size_t)m*320 + k] = hi;
  Xlo[(size_t)m*320 + k] = f2bf(v - bf2f(hi));
}

// ===== MFMA GEMM (bf16 3-split): C[M][N] = sum over 3K of Asel[m][kk] * Bt[n][k0] =====
template<bool BIAS>
__global__ __launch_bounds__(256) void k_mgemm(
    const unsigned short* __restrict__ Ahi, const unsigned short* __restrict__ Alo, int lda,
    const unsigned short* __restrict__ Bt, const float* __restrict__ bias,
    float* __restrict__ C, int N, int K) {
  __shared__ unsigned short As[64 * 40];   // rows padded to 40 ushorts (80 B)
  __shared__ unsigned short Bs[64 * 40];
  int tid = threadIdx.x;
  int wave = tid >> 6, lane = tid & 63;
  int quad = lane >> 4, l16 = lane & 15;
  int m0 = blockIdx.x << 6, n0 = blockIdx.y << 6;
  int K3 = 3 * K;
  int sr = tid >> 2;               // staging row 0..63
  int sc = (tid & 3) << 3;         // staging col 0,8,16,24
  f32x4 acc[4] = {};
  for (int k0 = 0; k0 < K3; k0 += 32) {
    int c = (k0 >= K) + (k0 >= 2*K);
    const unsigned short* Asrc = (c == 2) ? Alo : Ahi;
    int kk = k0 - c * K;
    ushort8 av = *(const ushort8*)(Asrc + (size_t)(m0 + sr) * lda + kk + sc);
    ushort8 bv = *(const ushort8*)(Bt + (size_t)(n0 + sr) * K3 + k0 + sc);
    *(ushort8*)&As[sr * 40 + sc] = av;
    *(ushort8*)&Bs[sr * 40 + sc] = bv;
    __syncthreads();
    short8 a  = *(const short8*)&As[(wave*16 + l16) * 40 + quad*8];
    short8 b0 = *(const short8*)&Bs[( 0 + l16) * 40 + quad*8];
    short8 b1 = *(const short8*)&Bs[(16 + l16) * 40 + quad*8];
    short8 b2 = *(const short8*)&Bs[(32 + l16) * 40 + quad*8];
    short8 b3 = *(const short8*)&Bs[(48 + l16) * 40 + quad*8];
    acc[0] = __builtin_amdgcn_mfma_f32_16x16x32_bf16(a, b0, acc[0], 0, 0, 0);
    acc[1] = __builtin_amdgcn_mfma_f32_16x16x32_bf16(a, b1, acc[1], 0, 0, 0);
    acc[2] = __builtin_amdgcn_mfma_f32_16x16x32_bf16(a, b2, acc[2], 0, 0, 0);
    acc[3] = __builtin_amdgcn_mfma_f32_16x16x32_bf16(a, b3, acc[3], 0, 0, 0);
    __syncthreads();
  }
  int row0 = m0 + wave * 16 + quad * 4;    // C/D: col=lane&15, row=quad*4+reg
#pragma unroll
  for (int t = 0; t < 4; t++) {
    int col = n0 + t * 16 + l16;
    float bb = BIAS ? bias[col] : 0.f;
#pragma unroll
    for (int r = 0; r < 4; r++)
      C[(size_t)(row0 + r) * N + col] = acc[t][r] + bb;
  }
}

// ===== fused conv GEMMs, split-K, atomic accumulate into zeroed Y =====
// blockIdx.z: [0,4) conv1 split, [4,12) conv2 split, [12,20) conv3 split
__global__ __launch_bounds__(256) void k_cgemm(
    const unsigned short* __restrict__ Ahi, const unsigned short* __restrict__ Alo,
    const unsigned short* __restrict__ B1, const unsigned short* __restrict__ B2c,
    const unsigned short* __restrict__ B3,
    float* __restrict__ Y1, float* __restrict__ Y2, float* __restrict__ Y3) {
  __shared__ unsigned short As[64 * 40];
  __shared__ unsigned short Bs[64 * 40];
  int z = blockIdx.z;
  const unsigned short* Bt; float* Y; int K, sidx, chunk;
  if (z < 4)       { Bt = B1;  Y = Y1; K = 1024; sidx = z;      chunk = 768;  }
  else if (z < 12) { Bt = B2c; Y = Y2; K = 3072; sidx = z - 4;  chunk = 1152; }
  else             { Bt = B3;  Y = Y3; K = 5120; sidx = z - 12; chunk = 1920; }
  int K3 = 3 * K;
  int ks = sidx * chunk, ke = ks + chunk;
  int tid = threadIdx.x;
  int wave = tid >> 6, lane = tid & 63;
  int quad = lane >> 4, l16 = lane & 15;
  int m0 = blockIdx.x << 6, n0 = blockIdx.y << 6;
  int sr = tid >> 2;
  int sc = (tid & 3) << 3;
  f32x4 acc[4] = {};
  for (int k0 = ks; k0 < ke; k0 += 32) {
    int c = (k0 >= K) + (k0 >= 2*K);
    const unsigned short* Asrc = (c == 2) ? Alo : Ahi;
    int kk = k0 - c * K;
    ushort8 av = *(const ushort8*)(Asrc + (size_t)(m0 + sr) * 1024 + kk + sc);
    ushort8 bv = *(const ushort8*)(Bt + (size_t)(n0 + sr) * K3 + k0 + sc);
    *(ushort8*)&As[sr * 40 + sc] = av;
    *(ushort8*)&Bs[sr * 40 + sc] = bv;
    __syncthreads();
    short8 a  = *(const short8*)&As[(wave*16 + l16) * 40 + quad*8];
    short8 b0 = *(const short8*)&Bs[( 0 + l16) * 40 + quad*8];
    short8 b1 = *(const short8*)&Bs[(16 + l16) * 40 + quad*8];
    short8 b2 = *(const short8*)&Bs[(32 + l16) * 40 + quad*8];
    short8 b3 = *(const short8*)&Bs[(48 + l16) * 40 + quad*8];
    acc[0] = __builtin_amdgcn_mfma_f32_16x16x32_bf16(a, b0, acc[0], 0, 0, 0);
    acc[1] = __builtin_amdgcn_mfma_f32_16x16x32_bf16(a, b1, acc[1], 0, 0, 0);
    acc[2] = __builtin_amdgcn_mfma_f32_16x16x32_bf16(a, b2, acc[2], 0, 0, 0);
    acc[3] = __builtin_amdgcn_mfma_f32_16x16x32_bf16(a, b3, acc[3], 0, 0, 0);
    __syncthreads();
  }
  int row0 = m0 + wave * 16 + quad * 4;
#pragma unroll
  for (int t = 0; t < 4; t++) {
    int col = n0 + t * 16 + l16;
#pragma unroll
    for (int r = 0; r < 4; r++)
      atomicAdd(&Y[(size_t)(row0 + r) * 192 + col], acc[t][r]);
  }
}

// ================= zero a float region (Y partial-sum init) =================
__global__ __launch_bounds__(256) void k_zero(float* __restrict__ p, int n4) {
  int idx = blockIdx.x * 256 + threadIdx.x;
  if (idx < n4) *(float4*)(p + (size_t)idx * 4) = make_float4(0.f, 0.f, 0.f, 0.f);
}

// ========== persistent recurrent kernel v5: unique slots + same-XCD L2 fast path =====
// 128 blocks; chain = bid&7 (0..5 active), tile = bid>>3 (0..15).
// Weights in VGPRs. h exchanged via a UNIQUE buffer slot per (chain, step):
// readers never revisit an address -> L1 always cold -> plain loads are L2-coherent.
// Every 64B line of a slot is written by exactly one block (fragment-ordered layout),
// so write-allocate cannot mix stale bytes.
// Runtime XCD detection (s_getreg HW_REG_XCC_ID): if a chain's 16 blocks share an XCD,
// use plain (L2) h stores/loads; else fall back to sc1 (L3) accesses. Flags are always
// sc1 (polled lines must bypass L1/L2). Correctness never depends on placement (G16).
// Plane layout (ushort idx within 16384-ush plane): elem(b,u) -> ((j*4+q)*64 + b)*8 + e
// with j=u>>5, q=(u>>3)&3, e=u&7 -> reader's 16B A-frag load is contiguous.
__global__ __launch_bounds__(256, 1) void k_steps(
    const unsigned short* __restrict__ WHB, const float* __restrict__ XP,
    float* __restrict__ hsQ, float* __restrict__ hsWp, float* __restrict__ hsRp,
    float* __restrict__ hsWr, float* __restrict__ hsRr,
    unsigned short* HxA, unsigned short* HxB,
    int* flags, int* det) {
  int bid = blockIdx.x;
  int chain = bid & 7;
  if (chain >= 6) return;                // 2 of 8 xcd-slots idle
  int tile = bid >> 3;                   // 0..15
  int dir = chain & 1, fam = chain >> 1;
  int tid = threadIdx.x;
  int wave = tid >> 6, lane = tid & 63;
  int quad = lane >> 4, l16 = lane & 15;
  int u0 = tile << 4;

  // ---- publish XCD id ----
  unsigned myxcd;
  asm volatile("s_getreg_b32 %0, hwreg(HW_REG_XCC_ID)" : "=s"(myxcd));
  if (tid == 0) AST(det + bid * 16, (int)myxcd + 1);

  // ---- load weight B-fragments into registers once (step-invariant) ----
  const unsigned short* wsrc = WHB + (((size_t)dir * 16 + tile) << 15);   // 64 rows x 512
  short8 Bh[4][8], Bl[4][8];
#pragma unroll
  for (int nf = 0; nf < 4; nf++)
#pragma unroll
    for (int j = 0; j < 8; j++) {
      const unsigned short* wr = wsrc + (nf * 16 + l16) * 512 + j * 32 + quad * 8;
      Bh[nf][j] = *(const short8*)(wr);
      Bl[nf][j] = *(const short8*)(wr + 256);
    }

  // ---- detect same-XCD chain ----
  __shared__ int s_fast;
  int idv = 0;
  if (tid < 16) {
    const int* dp = det + (tid * 8 + chain) * 16;
    int v;
    while ((v = ALD(dp)) == 0) __builtin_amdgcn_s_sleep(1);
    idv = v;
  }
  if (wave == 0) {
    int ref = __shfl(idv, 0, 64);
    unsigned long long bad = __ballot((lane < 16) && (idv != ref));
    if (lane == 0) s_fast = (bad == 0ULL);
  }
  __syncthreads();
  int fast = s_fast;

  int nsteps = (fam == 0) ? 40 : 16;
  int slot0 = (chain < 2) ? chain * 40 : 80 + (chain - 2) * 16;
  float creg[4] = {0.f, 0.f, 0.f, 0.f};
  int roff = (quad * 64 + wave * 16 + l16) * 8;             // reader frag base (ush), + j*2048
  int wj = tile >> 1;
  int wq = ((tile & 1) << 1) + (l16 >> 3);
  int wbase = ((wj * 4 + wq) * 64) * 4 + ((l16 & 7) >> 1);  // writer base (u32), + b*4

  for (int cs = 0; cs < nsteps; cs++) {
    // ---- phase params + XP prefetch (issued before the flag wait) ----
    int t, T, seg; float* hsb;
    if (fam == 0)     { t = cs;      T = 40; seg = 0;                         hsb = hsQ + (size_t)dir * 40 * BH; }
    else if (cs < 12) { t = cs;      T = 12; seg = (fam == 1) ? 2560 : 3584;  hsb = ((fam == 1) ? hsWp : hsWr) + (size_t)dir * 12 * BH; }
    else              { t = cs - 12; T = 4;  seg = (fam == 1) ? 3328 : 4352;  hsb = ((fam == 1) ? hsRp : hsRr) + (size_t)dir * 4 * BH; }
    int t_in = dir ? (T - 1 - t) : t;
    int u = u0 + l16;
    const float* xb = XP + (size_t)(seg + t_in * 64) * 2048 + dir * 1024 + u;
    float xi[4], xf[4], xg[4], xo[4];
#pragma unroll
    for (int r = 0; r < 4; r++) {
      const float* xr = xb + (size_t)(wave * 16 + quad * 4 + r) * 2048;
      xi[r] = xr[0]; xf[r] = xr[256]; xg[r] = xr[512]; xo[r] = xr[768];
    }

    f32x4 acc[4] = {};
    if (cs > 0) {
      int rs = slot0 + cs - 1;
      const unsigned short* Hb = (rs < 96) ? (HxA + (size_t)rs * 32768)
                                           : (HxB + (size_t)(rs - 96) * 32768);
      // ---- parallel flag wait (per-tile lines, sc1) ----
      if (tid < 16) {
        const int* fp = flags + ((rs * 16 + tid) << 4);
        while (ALD(fp) == 0) __builtin_amdgcn_s_sleep(1);
      }
      __syncthreads();
      // ---- h load direct to A-frags ----
      short8 ah[8], al[8];
      if (fast) {
#pragma unroll
        for (int j = 0; j < 8; j++) {
          ah[j] = *(const short8*)(Hb + j * 2048 + roff);
          al[j] = *(const short8*)(Hb + 16384 + j * 2048 + roff);
        }
      } else {
        const unsigned long long* ph = (const unsigned long long*)Hb;
        const unsigned long long* pl = ph + 4096;
        int r4 = roff >> 2;
        unsigned long long rv[32];
#pragma unroll
        for (int j = 0; j < 8; j++) { rv[2*j] = ALD(ph + j*512 + r4); rv[2*j+1] = ALD(ph + j*512 + r4 + 1); }
#pragma unroll
        for (int j = 0; j < 8; j++) { rv[16+2*j] = ALD(pl + j*512 + r4); rv[16+2*j+1] = ALD(pl + j*512 + r4 + 1); }
#pragma unroll
        for (int j = 0; j < 8; j++) { ah[j] = mk8(rv[2*j], rv[2*j+1]); al[j] = mk8(rv[16+2*j], rv[16+2*j+1]); }
      }
      // ---- bf16x3, all operands in registers ----
#pragma unroll
      for (int j = 0; j < 8; j++) {
        acc[0] = __builtin_amdgcn_mfma_f32_16x16x32_bf16(ah[j], Bh[0][j], acc[0], 0, 0, 0);
        acc[1] = __builtin_amdgcn_mfma_f32_16x16x32_bf16(ah[j], Bh[1][j], acc[1], 0, 0, 0);
        acc[2] = __builtin_amdgcn_mfma_f32_16x16x32_bf16(ah[j], Bh[2][j], acc[2], 0, 0, 0);
        acc[3] = __builtin_amdgcn_mfma_f32_16x16x32_bf16(ah[j], Bh[3][j], acc[3], 0, 0, 0);
      }
#pragma unroll
      for (int j = 0; j < 8; j++) {
        acc[0] = __builtin_amdgcn_mfma_f32_16x16x32_bf16(ah[j], Bl[0][j], acc[0], 0, 0, 0);
        acc[1] = __builtin_amdgcn_mfma_f32_16x16x32_bf16(ah[j], Bl[1][j], acc[1], 0, 0, 0);
        acc[2] = __builtin_amdgcn_mfma_f32_16x16x32_bf16(ah[j], Bl[2][j], acc[2], 0, 0, 0);
        acc[3] = __builtin_amdgcn_mfma_f32_16x16x32_bf16(ah[j], Bl[3][j], acc[3], 0, 0, 0);
      }
#pragma unroll
      for (int j = 0; j < 8; j++) {
        acc[0] = __builtin_amdgcn_mfma_f32_16x16x32_bf16(al[j], Bh[0][j], acc[0], 0, 0, 0);
        acc[1] = __builtin_amdgcn_mfma_f32_16x16x32_bf16(al[j], Bh[1][j], acc[1], 0, 0, 0);
        acc[2] = __builtin_amdgcn_mfma_f32_16x16x32_bf16(al[j], Bh[2][j], acc[2], 0, 0, 0);
        acc[3] = __builtin_amdgcn_mfma_f32_16x16x32_bf16(al[j], Bh[3][j], acc[3], 0, 0, 0);
      }
    }
    // ---- gates + state update ----
    float hnv[4];
#pragma unroll
    for (int r = 0; r < 4; r++) {
      float zi = acc[0][r] + xi[r];
      float zf = acc[1][r] + xf[r];
      float zg = acc[2][r] + xg[r];
      float zo = acc[3][r] + xo[r];
      float gi = 1.f / (1.f + expf(-zi));
      float gf = 1.f / (1.f + expf(-zf));
      float go = 1.f / (1.f + expf(-zo));
      float gg = tanhf(zg);
      float cn = gf * creg[r] + gi * gg;
      hnv[r] = go * tanhf(cn);
      creg[r] = cn;
    }
    int wslot = slot0 + cs;
    if (cs + 1 < nsteps) {
      unsigned short* Ho = (wslot < 96) ? (HxA + (size_t)wslot * 32768)
                                        : (HxB + (size_t)(wslot - 96) * 32768);
      unsigned int* ohw = (unsigned int*)Ho + wbase;
      unsigned int* olw = (unsigned int*)(Ho + 16384) + wbase;
#pragma unroll
      for (int r = 0; r < 4; r++) {
        int b = wave * 16 + quad * 4 + r;
        unsigned short h16 = f2bf(hnv[r]);
        unsigned short l16v = f2bf(hnv[r] - bf2f(h16));
        unsigned int pk = (unsigned int)h16 | ((unsigned int)l16v << 16);
        unsigned int pw = (unsigned int)__shfl_xor((int)pk, 1, 64);   // partner (u^1): e^1
        if ((lane & 1) == 0) {
          unsigned int hw = (pk & 0xFFFFu) | (pw << 16);
          unsigned int lw = (pk >> 16) | (pw & 0xFFFF0000u);
          if (fast) { ohw[b * 4] = hw; olw[b * 4] = lw; }
          else      { AST(ohw + b * 4, hw); AST(olw + b * 4, lw); }
        }
      }
      __syncthreads();                  // drains vmcnt(0): stores acked (L2 fast / L3 sc1)
      if (tid == 0)
        AST(flags + ((wslot * 16 + tile) << 4), 1);
    }
    // ---- hs fp32 writes, off the exchange critical path ----
    float* hout = hsb + (size_t)t * BH + u;
#pragma unroll
    for (int r = 0; r < 4; r++) {
      int b = wave * 16 + quad * 4 + r;
      hout[(size_t)b * 256] = hnv[r];
    }
  }
}

// ================= question_out as [b][s][h] =================
__global__ __launch_bounds__(256) void k_qo1(const float* __restrict__ hsQ, float* __restrict__ QT) {
  int idx = blockIdx.x * 256 + threadIdx.x;
  if (idx >= 64*40*512) return;
  int h = idx & 511; int t2 = idx >> 9; int s = t2 % 40; int b = t2 / 40;
  float v;
  if (h < 256) v = hsQ[(size_t)s * BH + b*256 + h];
  else         v = hsQ[(size_t)40 * BH + (size_t)(39 - s) * BH + b*256 + (h - 256)];
  QT[idx] = v;
}

// ================= relation tensors [b][r][h] fp32 + bf16-split, both calls ==============
__global__ __launch_bounds__(256) void k_rel(
    const float* __restrict__ hsWp, const float* __restrict__ hsRp,
    const float* __restrict__ hsWr, const float* __restrict__ hsRr,
    float* __restrict__ RELP, float* __restrict__ RELC,
    unsigned short* __restrict__ RPhi, unsigned short* __restrict__ RPlo,
    unsigned short* __restrict__ RChi, unsigned short* __restrict__ RClo) {
  int idx0 = blockIdx.x * 256 + threadIdx.x;
  if (idx0 >= 2*64*16*512) return;
  int call = idx0 >= 64*16*512;
  int idx = idx0 - call * 64*16*512;
  int h = idx & 511; int t2 = idx >> 9; int r = t2 & 15; int b = t2 >> 4;
  const float* hsW = call ? hsWr : hsWp;
  const float* hsR = call ? hsRr : hsRp;
  float v;
  if (r < 4) {
    if (h < 256) v = hsR[(size_t)r * BH + b*256 + h];
    else         v = hsR[(size_t)4 * BH + (size_t)(3 - r) * BH + b*256 + (h - 256)];
  } else {
    int t = r - 4;
    if (h < 256) v = hsW[(size_t)t * BH + b*256 + h];
    else         v = hsW[(size_t)12 * BH + (size_t)(11 - t) * BH + b*256 + (h - 256)];
  }
  unsigned short hi = f2bf(v);
  unsigned short lo = f2bf(v - bf2f(hi));
  if (call) { RELC[idx] = v; RChi[idx] = hi; RClo[idx] = lo; }
  else      { RELP[idx] = v; RPhi[idx] = hi; RPlo[idx] = lo; }
}

// ================= energy[b][r][s] =================
__global__ __launch_bounds__(256) void k_energy(
    const float* __restrict__ relW, const float* __restrict__ QT, float* __restrict__ EN) {
  int idx = blockIdx.x * 256 + threadIdx.x;
  if (idx >= 64*16*40) return;
  int s = idx % 40; int t = idx / 40; int r = t & 15; int b = t >> 4;
  const float* rw = relW + (size_t)(b*16 + r) * 512;
  const float* qv = QT   + (size_t)(b*40 + s) * 512;
  float acc = 0.f;
#pragma unroll 4
  for (int k = 0; k < 512; k += 4) {
    float4 a = *(const float4*)(rw + k);
    float4 c = *(const float4*)(qv + k);
    acc += a.x*c.x + a.y*c.y + a.z*c.z + a.w*c.w;
  }
  EN[idx] = acc;
}

// ================= softmax over 640 per b =================
__global__ __launch_bounds__(256) void k_softmax(float* __restrict__ EN) {
  int b = blockIdx.x; int tid = threadIdx.x;
  float* e = EN + b * 640;
  float v0 = e[tid] * 0.25f, v1 = e[tid + 256] * 0.25f;
  float v2 = (tid < 128) ? e[tid + 512] * 0.25f : NEG_INF;
  __shared__ float sh[256];
  sh[tid] = fmaxf(v0, fmaxf(v1, v2));
  __syncthreads();
  for (int st = 128; st > 0; st >>= 1) { if (tid < st) sh[tid] = fmaxf(sh[tid], sh[tid+st]); __syncthreads(); }
  float m = sh[0];
  __syncthreads();
  float e0 = expf(v0 - m), e1 = expf(v1 - m);
  float e2 = (tid < 128) ? expf(v2 - m) : 0.f;
  sh[tid] = e0 + e1 + e2;
  __syncthreads();
  for (int st = 128; st > 0; st >>= 1) { if (tid < st) sh[tid] += sh[tid+st]; __syncthreads(); }
  float inv = 1.f / sh[0];
  e[tid] = e0 * inv; e[tid + 256] = e1 * inv;
  if (tid < 128) e[tid + 512] = e2 * inv;
}

// ================= atten[b][s][h] =================
__global__ __launch_bounds__(256) void k_atten(
    const float* __restrict__ AL, const float* __restrict__ REL, float* __restrict__ ATT) {
  int idx = blockIdx.x * 256 + threadIdx.x;
  if (idx >= 64*40*512) return;
  int h = idx & 511; int t2 = idx >> 9; int s = t2 % 40; int b = t2 / 40;
  const float* al = AL + b * 640 + s;
  const float* rl = REL + (size_t)b * 16 * 512 + h;
  float acc = 0.f;
#pragma unroll
  for (int r = 0; r < 16; r++) acc += al[r*40] * rl[r*512];
  ATT[idx] = acc;
}

// ================= (QT - ATT) -> bf16 split =================
__global__ __launch_bounds__(256) void k_sub(
    const float* __restrict__ QT, const float* __restrict__ ATT,
    unsigned short* __restrict__ Dhi, unsigned short* __restrict__ Dlo) {
  int idx = blockIdx.x * 256 + threadIdx.x;
  if (idx >= 64*40*512) return;
  float v = QT[idx] - ATT[idx];
  unsigned short hi = f2bf(v);
  Dhi[idx] = hi; Dlo[idx] = f2bf(v - bf2f(hi));
}

// ================= pack M2[m][c] bf16-split, with zero tail pad =================
__global__ __launch_bounds__(256) void k_m2(
    const float* __restrict__ QO2, const float* __restrict__ ATT,
    unsigned short* __restrict__ M2hi, unsigned short* __restrict__ M2lo) {
  int idx = blockIdx.x * 256 + threadIdx.x;
  if (idx >= 2626048) return;
  float v = 0.f;
  if (idx < 2621440) {
    int c = idx & 1023; int m = idx >> 10;
    v = (c < 512) ? QO2[(size_t)m*512 + c] : ATT[(size_t)m*512 + (c - 512)];
  }
  unsigned short hi = f2bf(v);
  M2hi[idx] = hi; M2lo[idx] = f2bf(v - bf2f(hi));
}

// ================= pool(bias+relu+max over l) + score =================
__global__ __launch_bounds__(256) void k_pool(
    const float* __restrict__ Y1, const float* __restrict__ Y2, const float* __restrict__ Y3,
    const float* __restrict__ b1, const float* __restrict__ b2, const float* __restrict__ b3,
    const float* __restrict__ lw, float* __restrict__ out) {
  int b = blockIdx.x, o = threadIdx.x;
  float hv = 0.f;
  if (o < 150) {
    const float* y1 = Y1 + (size_t)b*40*192 + o;
    const float* y2 = Y2 + (size_t)b*40*192 + o;
    const float* y3 = Y3 + (size_t)b*40*192 + o;
    float m1 = NEG_INF, m2 = NEG_INF, m3 = NEG_INF;
#pragma unroll 4
    for (int l = 0; l < 40; l++) m1 = fmaxf(m1, y1[l*192]);
#pragma unroll 2
    for (int l = 0; l < 38; l++) m2 = fmaxf(m2, y2[l*192]);
#pragma unroll 2
    for (int l = 0; l < 36; l++) m3 = fmaxf(m3, y3[l*192]);
    float h = fmaxf(fmaxf(m1 + b1[o], m2 + b2[o]), m3 + b3[o]);
    hv = fmaxf(h, 0.f) * lw[o];
  }
  __shared__ float sh[256];
  sh[threadIdx.x] = hv;
  __syncthreads();
  for (int st = 128; st > 0; st >>= 1) { if (threadIdx.x < st) sh[threadIdx.x] += sh[threadIdx.x+st]; __syncthreads(); }
  if (threadIdx.x == 0) out[b] = sh[0];
}

// ================= host =================
extern "C" void kernel_launch(void* const* d_in, const int* in_sizes, int n_in,
                              void* d_out, int out_size, void* d_ws, size_t ws_size,
                              hipStream_t stream) {
  const int*   q    = (const int*)d_in[0];
  const int*   wrel = (const int*)d_in[1];
  const int*   rrel = (const int*)d_in[2];
  const int*   wprv = (const int*)d_in[3];
  const int*   rprv = (const int*)d_in[4];
  const float* we   = (const float*)d_in[5];
  const float* re   = (const float*)d_in[6];
  const float* Wih_f= (const float*)d_in[7];
  const float* Whh_f= (const float*)d_in[8];
  const float* b_f  = (const float*)d_in[9];
  const float* Wih_b= (const float*)d_in[10];
  const float* Whh_b= (const float*)d_in[11];
  const float* b_b  = (const float*)d_in[12];
  const float* W    = (const float*)d_in[13];
  const float* c1w  = (const float*)d_in[14];
  const float* c1b  = (const float*)d_in[15];
  const float* c2w  = (const float*)d_in[16];
  const float* c2b  = (const float*)d_in[17];
  const float* c3w  = (const float*)d_in[18];
  const float* c3b  = (const float*)d_in[19];
  const float* lw   = (const float*)d_in[20];
  const float* l2w  = (const float*)d_in[21];
  const float* l2b  = (const float*)d_in[22];
  float* out = (float*)d_out;
  float* ws  = (float*)d_ws;

  unsigned short* WHB = (unsigned short*)(ws + OFF_WQ);   // 1048576 ush (exact fit)
  float* B2   = ws + OFF_B2;
  unsigned short* XB3T  = (unsigned short*)(ws + OFF_XB3T);
  unsigned short* WB3T  = (unsigned short*)(ws + OFF_WB3T);
  unsigned short* L2B3T = (unsigned short*)(ws + OFF_L2B3T);
  unsigned short* C1B3T = (unsigned short*)(ws + OFF_C1B3T);
  unsigned short* C2B3T = (unsigned short*)(ws + OFF_C2B3T);
  unsigned short* C3B3T = (unsigned short*)(ws + OFF_C3B3T);
  unsigned short* Xhi   = (unsigned short*)(ws + OFF_XHI);
  unsigned short* Xlo   = (unsigned short*)(ws + OFF_XLO);
  float* XP   = ws + OFF_XP;
  float* HSQ  = ws + OFF_HSQ;
  float* HSWP = ws + OFF_HSWP;
  float* HSRP = ws + OFF_HSRP;
  float* HSWR = ws + OFF_HSWR;
  float* HSRR = ws + OFF_HSRR;
  int*   flags = (int*)(ws + OFF_CS);                     // 3072 slots x 64B
  int*   det   = flags + 49152;                           // 128 slots x 64B
  float* RELP = ws + OFF_RELP;
  float* RELC = ws + OFF_RELC;
  float* RELW = ws + OFF_RELW;
  float* EN   = ws + OFF_EN;
  // During k_steps: HxA = RELP..RELW (96 slots x 32768 ush), HxB = XB3T (48 slots).
  unsigned short* HxA = (unsigned short*)(ws + OFF_RELP);
  unsigned short* HxB = (unsigned short*)(ws + OFF_XB3T);
  // XP-region aliases (XP dead after k_steps)
  float* QO1  = XP;
  float* ATT  = XP + 1310720;
  float* QO2  = XP + 2621440;
  unsigned short* Dhi  = (unsigned short*)(XP + 3932160);
  unsigned short* Dlo  = (unsigned short*)(XP + 4587520);
  unsigned short* RPhi = (unsigned short*)(XP + 5242880);
  unsigned short* RPlo = (unsigned short*)(XP + 5505024);
  unsigned short* RChi = (unsigned short*)(XP + 5767168);
  unsigned short* RClo = (unsigned short*)(XP + 6029312);
  unsigned short* M2hi = (unsigned short*)(XP + 5242880);   // overwrites RP/RC (dead by then)
  unsigned short* M2lo = (unsigned short*)(XP + 6555904);
  float* Y1   = XP + 7868928;
  float* Y2   = XP + 8360448;
  float* Y3   = XP + 8851968;

  k_prep<<<15624, 256, 0, stream>>>(Whh_f, Whh_b, b_f, b_b, Wih_f, Wih_b, W, l2w,
                                    c1w, c2w, c3w,
                                    WHB, B2, XB3T, WB3T, L2B3T, C1B3T, C2B3T, C3B3T, flags);
  k_gather<<<NTOK, 320, 0, stream>>>(q, wrel, rrel, wprv, rprv, we, re, Xhi, Xlo);
  { dim3 g(72, 32); k_mgemm<true><<<g, 256, 0, stream>>>(Xhi, Xlo, 320, XB3T, B2, XP, 2048, 320); }

  // ---- all 40 recurrent steps in one persistent kernel (unique slots, XCD fast path) ----
  k_steps<<<128, 256, 0, stream>>>(WHB, XP, HSQ, HSWP, HSRP, HSWR, HSRR, HxA, HxB, flags, det);

  k_qo1<<<5120, 256, 0, stream>>>(HSQ, QO1);
  k_rel<<<4096, 256, 0, stream>>>(HSWP, HSRP, HSWR, HSRR, RELP, RELC, RPhi, RPlo, RChi, RClo);

  // ---- attention (previous hop) ----
  { dim3 g(16, 8); k_mgemm<false><<<g, 256, 0, stream>>>(RPhi, RPlo, 512, WB3T, nullptr, RELW, 512, 512); }
  k_energy<<<160, 256, 0, stream>>>(RELW, QO1, EN);
  k_softmax<<<64, 256, 0, stream>>>(EN);
  k_atten<<<5120, 256, 0, stream>>>(EN, RELP, ATT);
  k_sub<<<5120, 256, 0, stream>>>(QO1, ATT, Dhi, Dlo);
  { dim3 g(40, 8); k_mgemm<true><<<g, 256, 0, stream>>>(Dhi, Dlo, 512, L2B3T, l2b, QO2, 512, 512); }

  // ---- attention (current relation) ----
  { dim3 g(16, 8); k_mgemm<false><<<g, 256, 0, stream>>>(RChi, RClo, 512, WB3T, nullptr, RELW, 512, 512); }
  k_energy<<<160, 256, 0, stream>>>(RELW, QO2, EN);
  k_softmax<<<64, 256, 0, stream>>>(EN);
  k_atten<<<5120, 256, 0, stream>>>(EN, RELC, ATT);

  // ---- convs: fused split-K MFMA GEMM, atomic accumulate into zeroed Y ----
  k_m2<<<10258, 256, 0, stream>>>(QO2, ATT, M2hi, M2lo);
  k_zero<<<1440, 256, 0, stream>>>(Y1, 368640);   // zero Y1..Y3 (contiguous 1474560 fl)
  { dim3 g(40, 3, 20); k_cgemm<<<g, 256, 0, stream>>>(M2hi, M2lo, C1B3T, C2B3T, C3B3T, Y1, Y2, Y3); }
  k_pool<<<64, 256, 0, stream>>>(Y1, Y2, Y3, c1b, c2b, c3b, lw, out);
}

// Round 8
// 669.202 us; speedup vs baseline: 1.1803x; 1.0278x over previous
//
#include <hip/hip_runtime.h>
#include <math.h>

#define NEG_INF (-3.402823466e+38f)

typedef __attribute__((ext_vector_type(8))) short short8;
typedef __attribute__((ext_vector_type(8))) unsigned short ushort8;
typedef __attribute__((ext_vector_type(4))) float f32x4;

// ---- dims ----
constexpr int NTOK = 4608;              // 2560 Q + 768 Wp + 256 Rp + 768 Wr + 256 Rr
constexpr int BH = 64 * 256;            // one (b,u) plane

// ---- ws offsets (floats); ushort arrays use 2 elems per float slot ----
constexpr size_t OFF_WQ    = 0;                          // 524288 fl (= WHB 1048576 ush)
constexpr size_t OFF_B2    = OFF_WQ    + 524288;         // 2048
constexpr size_t OFF_XB3T  = OFF_B2    + 2048;           // 2048*960 us  = 983040 fl (k_steps: HxB)
constexpr size_t OFF_WB3T  = OFF_XB3T  + 983040;         // 512*1536 us  = 393216 fl
constexpr size_t OFF_L2B3T = OFF_WB3T  + 393216;         // 393216 fl
constexpr size_t OFF_CB3T  = OFF_L2B3T + 393216;         // 1408*3072 us = 2162688 fl (<= 2654208)
constexpr size_t OFF_XHI   = OFF_CB3T  + 2654208;        // 4608*320 us  = 737280 fl
constexpr size_t OFF_XLO   = OFF_XHI   + 737280;
constexpr size_t OFF_XP    = OFF_XLO   + 737280;         // 4608*2048 fp32 = 9437184
constexpr size_t OFF_HSQ   = OFF_XP    + 9437184;        // 1310720
constexpr size_t OFF_HSWP  = OFF_HSQ   + 1310720;        // 393216
constexpr size_t OFF_HSRP  = OFF_HSWP  + 393216;         // 131072
constexpr size_t OFF_HSWR  = OFF_HSRP  + 131072;         // 393216
constexpr size_t OFF_HSRR  = OFF_HSWR  + 393216;         // 131072
constexpr size_t OFF_CS    = OFF_HSRR  + 131072;         // 163840 (steps: flags + det)
constexpr size_t OFF_RELP  = OFF_CS    + 163840;         // 524288 (steps: HxA slots)
constexpr size_t OFF_RELC  = OFF_RELP  + 524288;         // 524288
constexpr size_t OFF_RELW  = OFF_RELC  + 524288;         // 524288
constexpr size_t OFF_EN    = OFF_RELW  + 524288;         // 40960
// end = OFF_EN + 40960 = 19998720 floats (~80 MB)
// During k_steps: HxA = RELP..RELW (96 slots x 32768 ush), HxB = XB3T (48 slots).
// XP region aliases (XP dead after k_steps):
//   QO1 +0 (1310720), ATT +1310720, QO2 +2621440,
//   Dhi +3932160 (655360 fl), Dlo +4587520,
//   RPhi +5242880, RPlo +5505024, RChi +5767168, RClo +6029312 (dead before k_m2)
//   M2hi +5242880 (1313024 fl), M2lo +6555904 (end 7868928)
//   Y (conv tap-GEMM out) +0: 2560*1408 = 3604480 fl (QO1/ATT/QO2/D dead by then; M2 at +5242880 safe)

__device__ inline unsigned short f2bf(float f) {
  unsigned int u = __float_as_uint(f);
  u += 0x7FFFu + ((u >> 16) & 1u);          // RNE
  return (unsigned short)(u >> 16);
}
__device__ inline float bf2f(unsigned short h) {
  return __uint_as_float(((unsigned int)h) << 16);
}
__device__ inline short8 mk8(unsigned long long a, unsigned long long b) {
  union { unsigned long long q[2]; short8 s; } u;
  u.q[0] = a; u.q[1] = b; return u.s;
}
#define ALD(p) __hip_atomic_load((p), __ATOMIC_RELAXED, __HIP_MEMORY_SCOPE_AGENT)
#define AST(p, v) __hip_atomic_store((p), (v), __ATOMIC_RELAXED, __HIP_MEMORY_SCOPE_AGENT)

// ================= prep: WHB + bias + XB3T/WB3T/L2B3T + CB3T (tap-expanded convs) =====
// WHB layout: [dir][tile 16][row = g*16+uu (64)][hi k 0..255 | lo k 0..255]
// CB3T: B3T pack [n=tap*150+o (1408 pad)][3K, K=1024]; taps: 0=c1, 1..3=c2 kw, 4..8=c3 kw.
__global__ __launch_bounds__(256) void k_prep(
    const float* __restrict__ Whh_f, const float* __restrict__ Whh_b,
    const float* __restrict__ b_f,   const float* __restrict__ b_b,
    const float* __restrict__ Wih_f, const float* __restrict__ Wih_b,
    const float* __restrict__ Wat,   const float* __restrict__ l2w,
    const float* __restrict__ c1w, const float* __restrict__ c2w, const float* __restrict__ c3w,
    unsigned short* __restrict__ WHB, float* __restrict__ B2,
    unsigned short* __restrict__ XB3T, unsigned short* __restrict__ WB3T,
    unsigned short* __restrict__ L2B3T, unsigned short* __restrict__ CB3T,
    int* __restrict__ flags) {
  int idx = blockIdx.x * 256 + threadIdx.x;
  if (idx < 3072)                           // reset per-slot step flags (64B apart each)
    AST(flags + idx * 16, 0);
  else if (idx < 3200)                      // reset det slots (det = flags + 49152 ints)
    AST(flags + 49152 + (idx - 3072) * 16, 0);
  if (idx < 1048576) {                      // WHB
    int e = idx & 511;                      // k + 256*isLo
    int k = e & 255, isLo = e >> 8;
    int row = (idx >> 9) & 63;              // g*16+uu
    int tile = (idx >> 15) & 15;
    int d = idx >> 19;
    int g = row >> 4, uu = row & 15;
    int u = tile * 16 + uu;
    const float* Wh = d ? Whh_b : Whh_f;
    float w = Wh[(size_t)(g * 256 + u) * 256 + k];
    unsigned short hi = f2bf(w);
    WHB[idx] = isLo ? f2bf(w - bf2f(hi)) : hi;
    return;
  }
  idx -= 1048576;
  if (idx < 2048) { B2[idx] = (idx < 1024) ? b_f[idx] : b_b[idx-1024]; return; }
  idx -= 2048;
  unsigned short* dst; int n, k, K;
  float w;
  if (idx < 655360) {                       // XB3T: n<2048, Kp=320 (src K=300)
    n = idx / 320; k = idx % 320; K = 320; dst = XB3T;
    w = (k < 300) ? ((n < 1024) ? Wih_f[(size_t)n*300 + k] : Wih_b[(size_t)(n-1024)*300 + k]) : 0.f;
  } else if ((idx -= 655360) < 262144) {    // WB3T: B[k][n] = Wat[k][n]
    n = idx >> 9; k = idx & 511; K = 512; dst = WB3T;
    w = Wat[(size_t)k*512 + n];
  } else if ((idx -= 262144) < 262144) {    // L2B3T: B[k][n] = l2w[n][k]
    n = idx >> 9; k = idx & 511; K = 512; dst = L2B3T;
    w = l2w[(size_t)n*512 + k];
  } else if ((idx -= 262144) < 1441792) {   // CB3T: n<1408, K=1024
    n = idx >> 10; k = idx & 1023; K = 1024; dst = CB3T;
    if (n < 1350) {
      int t = n / 150, o = n % 150;
      w = (t == 0) ? c1w[(size_t)o*1024 + k]
        : (t < 4)  ? c2w[((size_t)o*1024 + k)*3 + (t-1)]
                   : c3w[((size_t)o*1024 + k)*5 + (t-4)];
    } else w = 0.f;
  } else return;
  unsigned short hi = f2bf(w);
  unsigned short lo = f2bf(w - bf2f(hi));
  size_t base = (size_t)n * (3*K);
  dst[base + k] = hi;
  dst[base + K + k] = lo;
  dst[base + 2*K + k] = hi;
}

// ================= gather embeddings -> bf16 split, K padded to 320 =================
__global__ __launch_bounds__(320) void k_gather(
    const int* __restrict__ q,  const int* __restrict__ wr, const int* __restrict__ rr,
    const int* __restrict__ wp, const int* __restrict__ rp,
    const float* __restrict__ we, const float* __restrict__ re,
    unsigned short* __restrict__ Xhi, unsigned short* __restrict__ Xlo) {
  int m = blockIdx.x, k = threadIdx.x;
  const float* emb; int row;
  if (m < 2560)      { int t=m>>6,    b=m&63; row = q [b*40+t]; emb = we; }
  else if (m < 3328) { int mm=m-2560; int t=mm>>6,b=mm&63; row = wp[b*12+t]; emb = we; }
  else if (m < 3584) { int mm=m-3328; int t=mm>>6,b=mm&63; row = rp[b*4 +t]; emb = re; }
  else if (m < 4352) { int mm=m-3584; int t=mm>>6,b=mm&63; row = wr[b*12+t]; emb = we; }
  else               { int mm=m-4352; int t=mm>>6,b=mm&63; row = rr[b*4 +t]; emb = re; }
  float v = (k < 300) ? emb[(size_t)row*300 + k] : 0.f;
  unsigned short hi = f2bf(v);
  Xhi[(size_t)m*320 + k] = hi;
  Xlo[(size_t)m*320 + k] = f2bf(v - bf2f(hi));
}

// ===== MFMA GEMM 64² tile (bf16 3-split), for small/narrow GEMMs =====
template<bool BIAS>
__global__ __launch_bounds__(256) void k_mgemm(
    const unsigned short* __restrict__ Ahi, const unsigned short* __restrict__ Alo, int lda,
    const unsigned short* __restrict__ Bt, const float* __restrict__ bias,
    float* __restrict__ C, int N, int K) {
  __shared__ unsigned short As[64 * 40];   // rows padded to 40 ushorts (80 B)
  __shared__ unsigned short Bs[64 * 40];
  int tid = threadIdx.x;
  int wave = tid >> 6, lane = tid & 63;
  int quad = lane >> 4, l16 = lane & 15;
  int m0 = blockIdx.x << 6, n0 = blockIdx.y << 6;
  int K3 = 3 * K;
  int sr = tid >> 2;               // staging row 0..63
  int sc = (tid & 3) << 3;         // staging col 0,8,16,24
  f32x4 acc[4] = {};
  for (int k0 = 0; k0 < K3; k0 += 32) {
    int c = (k0 >= K) + (k0 >= 2*K);
    const unsigned short* Asrc = (c == 2) ? Alo : Ahi;
    int kk = k0 - c * K;
    ushort8 av = *(const ushort8*)(Asrc + (size_t)(m0 + sr) * lda + kk + sc);
    ushort8 bv = *(const ushort8*)(Bt + (size_t)(n0 + sr) * K3 + k0 + sc);
    *(ushort8*)&As[sr * 40 + sc] = av;
    *(ushort8*)&Bs[sr * 40 + sc] = bv;
    __syncthreads();
    short8 a  = *(const short8*)&As[(wave*16 + l16) * 40 + quad*8];
    short8 b0 = *(const short8*)&Bs[( 0 + l16) * 40 + quad*8];
    short8 b1 = *(const short8*)&Bs[(16 + l16) * 40 + quad*8];
    short8 b2 = *(const short8*)&Bs[(32 + l16) * 40 + quad*8];
    short8 b3 = *(const short8*)&Bs[(48 + l16) * 40 + quad*8];
    acc[0] = __builtin_amdgcn_mfma_f32_16x16x32_bf16(a, b0, acc[0], 0, 0, 0);
    acc[1] = __builtin_amdgcn_mfma_f32_16x16x32_bf16(a, b1, acc[1], 0, 0, 0);
    acc[2] = __builtin_amdgcn_mfma_f32_16x16x32_bf16(a, b2, acc[2], 0, 0, 0);
    acc[3] = __builtin_amdgcn_mfma_f32_16x16x32_bf16(a, b3, acc[3], 0, 0, 0);
    __syncthreads();
  }
  int row0 = m0 + wave * 16 + quad * 4;    // C/D: col=lane&15, row=quad*4+reg
#pragma unroll
  for (int t = 0; t < 4; t++) {
    int col = n0 + t * 16 + l16;
    float bb = BIAS ? bias[col] : 0.f;
#pragma unroll
    for (int r = 0; r < 4; r++)
      C[(size_t)(row0 + r) * N + col] = acc[t][r] + bb;
  }
}

// ===== MFMA GEMM 128² tile (bf16 3-split), BK=64, 4 waves x 4x4 frags (m93 structure) =====
// Requires M%128==0, N%128==0, K%64==0.
template<bool BIAS>
__global__ __launch_bounds__(256) void k_bgemm(
    const unsigned short* __restrict__ Ahi, const unsigned short* __restrict__ Alo, int lda,
    const unsigned short* __restrict__ Bt, const float* __restrict__ bias,
    float* __restrict__ C, int N, int K) {
  __shared__ unsigned short As[128 * 64];  // [row][k] linear, 128B rows
  __shared__ unsigned short Bs[128 * 64];  // [n][k] linear
  int tid = threadIdx.x;
  int wave = tid >> 6, lane = tid & 63;
  int quad = lane >> 4, l16 = lane & 15;
  int wm = wave >> 1, wn = wave & 1;       // 2x2 wave grid, each wave 64x64
  int m0 = blockIdx.x << 7, n0 = blockIdx.y << 7;
  int K3 = 3 * K;
  f32x4 acc[4][4] = {};
  for (int k0 = 0; k0 < K3; k0 += 64) {
    int c = (k0 >= K) + (k0 >= 2*K);
    const unsigned short* Asrc = (c == 2) ? Alo : Ahi;
    int kk = k0 - c * K;
    // stage 16KB each of A,B: 1024 chunks of 16B; thread handles 4 chunks per matrix
#pragma unroll
    for (int j = 0; j < 4; j++) {
      int ci = j * 256 + tid;
      int r = ci >> 3, c8 = (ci & 7) << 3;
      ushort8 av = *(const ushort8*)(Asrc + (size_t)(m0 + r) * lda + kk + c8);
      ushort8 bv = *(const ushort8*)(Bt + (size_t)(n0 + r) * K3 + k0 + c8);
      *(ushort8*)&As[ci * 8] = av;
      *(ushort8*)&Bs[ci * 8] = bv;
    }
    __syncthreads();
#pragma unroll
    for (int s = 0; s < 2; s++) {
      short8 af[4], bf[4];
#pragma unroll
      for (int f = 0; f < 4; f++) {
        af[f] = *(const short8*)&As[(wm*64 + f*16 + l16) * 64 + s*32 + quad*8];
        bf[f] = *(const short8*)&Bs[(wn*64 + f*16 + l16) * 64 + s*32 + quad*8];
      }
#pragma unroll
      for (int fm = 0; fm < 4; fm++)
#pragma unroll
        for (int fn = 0; fn < 4; fn++)
          acc[fm][fn] = __builtin_amdgcn_mfma_f32_16x16x32_bf16(af[fm], bf[fn], acc[fm][fn], 0, 0, 0);
    }
    __syncthreads();
  }
#pragma unroll
  for (int fm = 0; fm < 4; fm++) {
    int row0 = m0 + wm*64 + fm*16 + quad*4;
#pragma unroll
    for (int fn = 0; fn < 4; fn++) {
      int col = n0 + wn*64 + fn*16 + l16;
      float bb = BIAS ? bias[col] : 0.f;
#pragma unroll
      for (int r = 0; r < 4; r++)
        C[(size_t)(row0 + r) * N + col] = acc[fm][fn][r] + bb;
    }
  }
}

// ========== persistent recurrent kernel v5: unique slots + same-XCD L2 fast path =====
__global__ __launch_bounds__(256, 1) void k_steps(
    const unsigned short* __restrict__ WHB, const float* __restrict__ XP,
    float* __restrict__ hsQ, float* __restrict__ hsWp, float* __restrict__ hsRp,
    float* __restrict__ hsWr, float* __restrict__ hsRr,
    unsigned short* HxA, unsigned short* HxB,
    int* flags, int* det) {
  int bid = blockIdx.x;
  int chain = bid & 7;
  if (chain >= 6) return;                // 2 of 8 xcd-slots idle
  int tile = bid >> 3;                   // 0..15
  int dir = chain & 1, fam = chain >> 1;
  int tid = threadIdx.x;
  int wave = tid >> 6, lane = tid & 63;
  int quad = lane >> 4, l16 = lane & 15;
  int u0 = tile << 4;

  unsigned myxcd;
  asm volatile("s_getreg_b32 %0, hwreg(HW_REG_XCC_ID)" : "=s"(myxcd));
  if (tid == 0) AST(det + bid * 16, (int)myxcd + 1);

  const unsigned short* wsrc = WHB + (((size_t)dir * 16 + tile) << 15);
  short8 Bh[4][8], Bl[4][8];
#pragma unroll
  for (int nf = 0; nf < 4; nf++)
#pragma unroll
    for (int j = 0; j < 8; j++) {
      const unsigned short* wr = wsrc + (nf * 16 + l16) * 512 + j * 32 + quad * 8;
      Bh[nf][j] = *(const short8*)(wr);
      Bl[nf][j] = *(const short8*)(wr + 256);
    }

  __shared__ int s_fast;
  int idv = 0;
  if (tid < 16) {
    const int* dp = det + (tid * 8 + chain) * 16;
    int v;
    while ((v = ALD(dp)) == 0) __builtin_amdgcn_s_sleep(1);
    idv = v;
  }
  if (wave == 0) {
    int ref = __shfl(idv, 0, 64);
    unsigned long long bad = __ballot((lane < 16) && (idv != ref));
    if (lane == 0) s_fast = (bad == 0ULL);
  }
  __syncthreads();
  int fast = s_fast;

  int nsteps = (fam == 0) ? 40 : 16;
  int slot0 = (chain < 2) ? chain * 40 : 80 + (chain - 2) * 16;
  float creg[4] = {0.f, 0.f, 0.f, 0.f};
  int roff = (quad * 64 + wave * 16 + l16) * 8;
  int wj = tile >> 1;
  int wq = ((tile & 1) << 1) + (l16 >> 3);
  int wbase = ((wj * 4 + wq) * 64) * 4 + ((l16 & 7) >> 1);

  for (int cs = 0; cs < nsteps; cs++) {
    int t, T, seg; float* hsb;
    if (fam == 0)     { t = cs;      T = 40; seg = 0;                         hsb = hsQ + (size_t)dir * 40 * BH; }
    else if (cs < 12) { t = cs;      T = 12; seg = (fam == 1) ? 2560 : 3584;  hsb = ((fam == 1) ? hsWp : hsWr) + (size_t)dir * 12 * BH; }
    else              { t = cs - 12; T = 4;  seg = (fam == 1) ? 3328 : 4352;  hsb = ((fam == 1) ? hsRp : hsRr) + (size_t)dir * 4 * BH; }
    int t_in = dir ? (T - 1 - t) : t;
    int u = u0 + l16;
    const float* xb = XP + (size_t)(seg + t_in * 64) * 2048 + dir * 1024 + u;
    float xi[4], xf[4], xg[4], xo[4];
#pragma unroll
    for (int r = 0; r < 4; r++) {
      const float* xr = xb + (size_t)(wave * 16 + quad * 4 + r) * 2048;
      xi[r] = xr[0]; xf[r] = xr[256]; xg[r] = xr[512]; xo[r] = xr[768];
    }

    f32x4 acc[4] = {};
    if (cs > 0) {
      int rs = slot0 + cs - 1;
      const unsigned short* Hb = (rs < 96) ? (HxA + (size_t)rs * 32768)
                                           : (HxB + (size_t)(rs - 96) * 32768);
      if (tid < 16) {
        const int* fp = flags + ((rs * 16 + tid) << 4);
        while (ALD(fp) == 0) __builtin_amdgcn_s_sleep(1);
      }
      __syncthreads();
      short8 ah[8], al[8];
      if (fast) {
#pragma unroll
        for (int j = 0; j < 8; j++) {
          ah[j] = *(const short8*)(Hb + j * 2048 + roff);
          al[j] = *(const short8*)(Hb + 16384 + j * 2048 + roff);
        }
      } else {
        const unsigned long long* ph = (const unsigned long long*)Hb;
        const unsigned long long* pl = ph + 4096;
        int r4 = roff >> 2;
        unsigned long long rv[32];
#pragma unroll
        for (int j = 0; j < 8; j++) { rv[2*j] = ALD(ph + j*512 + r4); rv[2*j+1] = ALD(ph + j*512 + r4 + 1); }
#pragma unroll
        for (int j = 0; j < 8; j++) { rv[16+2*j] = ALD(pl + j*512 + r4); rv[16+2*j+1] = ALD(pl + j*512 + r4 + 1); }
#pragma unroll
        for (int j = 0; j < 8; j++) { ah[j] = mk8(rv[2*j], rv[2*j+1]); al[j] = mk8(rv[16+2*j], rv[16+2*j+1]); }
      }
#pragma unroll
      for (int j = 0; j < 8; j++) {
        acc[0] = __builtin_amdgcn_mfma_f32_16x16x32_bf16(ah[j], Bh[0][j], acc[0], 0, 0, 0);
        acc[1] = __builtin_amdgcn_mfma_f32_16x16x32_bf16(ah[j], Bh[1][j], acc[1], 0, 0, 0);
        acc[2] = __builtin_amdgcn_mfma_f32_16x16x32_bf16(ah[j], Bh[2][j], acc[2], 0, 0, 0);
        acc[3] = __builtin_amdgcn_mfma_f32_16x16x32_bf16(ah[j], Bh[3][j], acc[3], 0, 0, 0);
      }
#pragma unroll
      for (int j = 0; j < 8; j++) {
        acc[0] = __builtin_amdgcn_mfma_f32_16x16x32_bf16(ah[j], Bl[0][j], acc[0], 0, 0, 0);
        acc[1] = __builtin_amdgcn_mfma_f32_16x16x32_bf16(ah[j], Bl[1][j], acc[1], 0, 0, 0);
        acc[2] = __builtin_amdgcn_mfma_f32_16x16x32_bf16(ah[j], Bl[2][j], acc[2], 0, 0, 0);
        acc[3] = __builtin_amdgcn_mfma_f32_16x16x32_bf16(ah[j], Bl[3][j], acc[3], 0, 0, 0);
      }
#pragma unroll
      for (int j = 0; j < 8; j++) {
        acc[0] = __builtin_amdgcn_mfma_f32_16x16x32_bf16(al[j], Bh[0][j], acc[0], 0, 0, 0);
        acc[1] = __builtin_amdgcn_mfma_f32_16x16x32_bf16(al[j], Bh[1][j], acc[1], 0, 0, 0);
        acc[2] = __builtin_amdgcn_mfma_f32_16x16x32_bf16(al[j], Bh[2][j], acc[2], 0, 0, 0);
        acc[3] = __builtin_amdgcn_mfma_f32_16x16x32_bf16(al[j], Bh[3][j], acc[3], 0, 0, 0);
      }
    }
    float hnv[4];
#pragma unroll
    for (int r = 0; r < 4; r++) {
      float zi = acc[0][r] + xi[r];
      float zf = acc[1][r] + xf[r];
      float zg = acc[2][r] + xg[r];
      float zo = acc[3][r] + xo[r];
      float gi = 1.f / (1.f + expf(-zi));
      float gf = 1.f / (1.f + expf(-zf));
      float go = 1.f / (1.f + expf(-zo));
      float gg = tanhf(zg);
      float cn = gf * creg[r] + gi * gg;
      hnv[r] = go * tanhf(cn);
      creg[r] = cn;
    }
    int wslot = slot0 + cs;
    if (cs + 1 < nsteps) {
      unsigned short* Ho = (wslot < 96) ? (HxA + (size_t)wslot * 32768)
                                        : (HxB + (size_t)(wslot - 96) * 32768);
      unsigned int* ohw = (unsigned int*)Ho + wbase;
      unsigned int* olw = (unsigned int*)(Ho + 16384) + wbase;
#pragma unroll
      for (int r = 0; r < 4; r++) {
        int b = wave * 16 + quad * 4 + r;
        unsigned short h16 = f2bf(hnv[r]);
        unsigned short l16v = f2bf(hnv[r] - bf2f(h16));
        unsigned int pk = (unsigned int)h16 | ((unsigned int)l16v << 16);
        unsigned int pw = (unsigned int)__shfl_xor((int)pk, 1, 64);
        if ((lane & 1) == 0) {
          unsigned int hw = (pk & 0xFFFFu) | (pw << 16);
          unsigned int lw = (pk >> 16) | (pw & 0xFFFF0000u);
          if (fast) { ohw[b * 4] = hw; olw[b * 4] = lw; }
          else      { AST(ohw + b * 4, hw); AST(olw + b * 4, lw); }
        }
      }
      __syncthreads();
      if (tid == 0)
        AST(flags + ((wslot * 16 + tile) << 4), 1);
    }
    float* hout = hsb + (size_t)t * BH + u;
#pragma unroll
    for (int r = 0; r < 4; r++) {
      int b = wave * 16 + quad * 4 + r;
      hout[(size_t)b * 256] = hnv[r];
    }
  }
}

// ================= question_out as [b][s][h] =================
__global__ __launch_bounds__(256) void k_qo1(const float* __restrict__ hsQ, float* __restrict__ QT) {
  int idx = blockIdx.x * 256 + threadIdx.x;
  if (idx >= 64*40*512) return;
  int h = idx & 511; int t2 = idx >> 9; int s = t2 % 40; int b = t2 / 40;
  float v;
  if (h < 256) v = hsQ[(size_t)s * BH + b*256 + h];
  else         v = hsQ[(size_t)40 * BH + (size_t)(39 - s) * BH + b*256 + (h - 256)];
  QT[idx] = v;
}

// ================= relation tensors [b][r][h] fp32 + bf16-split, both calls ==============
__global__ __launch_bounds__(256) void k_rel(
    const float* __restrict__ hsWp, const float* __restrict__ hsRp,
    const float* __restrict__ hsWr, const float* __restrict__ hsRr,
    float* __restrict__ RELP, float* __restrict__ RELC,
    unsigned short* __restrict__ RPhi, unsigned short* __restrict__ RPlo,
    unsigned short* __restrict__ RChi, unsigned short* __restrict__ RClo) {
  int idx0 = blockIdx.x * 256 + threadIdx.x;
  if (idx0 >= 2*64*16*512) return;
  int call = idx0 >= 64*16*512;
  int idx = idx0 - call * 64*16*512;
  int h = idx & 511; int t2 = idx >> 9; int r = t2 & 15; int b = t2 >> 4;
  const float* hsW = call ? hsWr : hsWp;
  const float* hsR = call ? hsRr : hsRp;
  float v;
  if (r < 4) {
    if (h < 256) v = hsR[(size_t)r * BH + b*256 + h];
    else         v = hsR[(size_t)4 * BH + (size_t)(3 - r) * BH + b*256 + (h - 256)];
  } else {
    int t = r - 4;
    if (h < 256) v = hsW[(size_t)t * BH + b*256 + h];
    else         v = hsW[(size_t)12 * BH + (size_t)(11 - t) * BH + b*256 + (h - 256)];
  }
  unsigned short hi = f2bf(v);
  unsigned short lo = f2bf(v - bf2f(hi));
  if (call) { RELC[idx] = v; RChi[idx] = hi; RClo[idx] = lo; }
  else      { RELP[idx] = v; RPhi[idx] = hi; RPlo[idx] = lo; }
}

// ================= energy[b][r][s] =================
__global__ __launch_bounds__(256) void k_energy(
    const float* __restrict__ relW, const float* __restrict__ QT, float* __restrict__ EN) {
  int idx = blockIdx.x * 256 + threadIdx.x;
  if (idx >= 64*16*40) return;
  int s = idx % 40; int t = idx / 40; int r = t & 15; int b = t >> 4;
  const float* rw = relW + (size_t)(b*16 + r) * 512;
  const float* qv = QT   + (size_t)(b*40 + s) * 512;
  float acc = 0.f;
#pragma unroll 4
  for (int k = 0; k < 512; k += 4) {
    float4 a = *(const float4*)(rw + k);
    float4 c = *(const float4*)(qv + k);
    acc += a.x*c.x + a.y*c.y + a.z*c.z + a.w*c.w;
  }
  EN[idx] = acc;
}

// ================= softmax over 640 per b =================
__global__ __launch_bounds__(256) void k_softmax(float* __restrict__ EN) {
  int b = blockIdx.x; int tid = threadIdx.x;
  float* e = EN + b * 640;
  float v0 = e[tid] * 0.25f, v1 = e[tid + 256] * 0.25f;
  float v2 = (tid < 128) ? e[tid + 512] * 0.25f : NEG_INF;
  __shared__ float sh[256];
  sh[tid] = fmaxf(v0, fmaxf(v1, v2));
  __syncthreads();
  for (int st = 128; st > 0; st >>= 1) { if (tid < st) sh[tid] = fmaxf(sh[tid], sh[tid+st]); __syncthreads(); }
  float m = sh[0];
  __syncthreads();
  float e0 = expf(v0 - m), e1 = expf(v1 - m);
  float e2 = (tid < 128) ? expf(v2 - m) : 0.f;
  sh[tid] = e0 + e1 + e2;
  __syncthreads();
  for (int st = 128; st > 0; st >>= 1) { if (tid < st) sh[tid] += sh[tid+st]; __syncthreads(); }
  float inv = 1.f / sh[0];
  e[tid] = e0 * inv; e[tid + 256] = e1 * inv;
  if (tid < 128) e[tid + 512] = e2 * inv;
}

// ================= atten[b][s][h] =================
__global__ __launch_bounds__(256) void k_atten(
    const float* __restrict__ AL, const float* __restrict__ REL, float* __restrict__ ATT) {
  int idx = blockIdx.x * 256 + threadIdx.x;
  if (idx >= 64*40*512) return;
  int h = idx & 511; int t2 = idx >> 9; int s = t2 % 40; int b = t2 / 40;
  const float* al = AL + b * 640 + s;
  const float* rl = REL + (size_t)b * 16 * 512 + h;
  float acc = 0.f;
#pragma unroll
  for (int r = 0; r < 16; r++) acc += al[r*40] * rl[r*512];
  ATT[idx] = acc;
}

// ================= (QT - ATT) -> bf16 split =================
__global__ __launch_bounds__(256) void k_sub(
    const float* __restrict__ QT, const float* __restrict__ ATT,
    unsigned short* __restrict__ Dhi, unsigned short* __restrict__ Dlo) {
  int idx = blockIdx.x * 256 + threadIdx.x;
  if (idx >= 64*40*512) return;
  float v = QT[idx] - ATT[idx];
  unsigned short hi = f2bf(v);
  Dhi[idx] = hi; Dlo[idx] = f2bf(v - bf2f(hi));
}

// ================= pack M2[m][c] bf16-split, with zero tail pad =================
__global__ __launch_bounds__(256) void k_m2(
    const float* __restrict__ QO2, const float* __restrict__ ATT,
    unsigned short* __restrict__ M2hi, unsigned short* __restrict__ M2lo) {
  int idx = blockIdx.x * 256 + threadIdx.x;
  if (idx >= 2626048) return;
  float v = 0.f;
  if (idx < 2621440) {
    int c = idx & 1023; int m = idx >> 10;
    v = (c < 512) ? QO2[(size_t)m*512 + c] : ATT[(size_t)m*512 + (c - 512)];
  }
  unsigned short hi = f2bf(v);
  M2hi[idx] = hi; M2lo[idx] = f2bf(v - bf2f(hi));
}

// ================= pool over tap-expanded Y[2560][1408] + score =================
// Y[(b*40+l)*1408 + t*150 + o]; y1=T0; y2[l]=T1[l]+T2[l+1]+T3[l+2]; y3[l]=sum T4..8 shifted.
__global__ __launch_bounds__(256) void k_pool(
    const float* __restrict__ Y,
    const float* __restrict__ b1, const float* __restrict__ b2, const float* __restrict__ b3,
    const float* __restrict__ lw, float* __restrict__ out) {
  int b = blockIdx.x, o = threadIdx.x;
  float hv = 0.f;
  if (o < 150) {
    const float* yb = Y + (size_t)b * 40 * 1408 + o;
    float m1 = NEG_INF, m2 = NEG_INF, m3 = NEG_INF;
#pragma unroll 4
    for (int l = 0; l < 40; l++) m1 = fmaxf(m1, yb[l*1408]);
#pragma unroll 2
    for (int l = 0; l < 38; l++)
      m2 = fmaxf(m2, yb[l*1408 + 150] + yb[(l+1)*1408 + 300] + yb[(l+2)*1408 + 450]);
#pragma unroll 2
    for (int l = 0; l < 36; l++) {
      float s = yb[l*1408 + 600] + yb[(l+1)*1408 + 750] + yb[(l+2)*1408 + 900]
              + yb[(l+3)*1408 + 1050] + yb[(l+4)*1408 + 1200];
      m3 = fmaxf(m3, s);
    }
    float h = fmaxf(fmaxf(m1 + b1[o], m2 + b2[o]), m3 + b3[o]);
    hv = fmaxf(h, 0.f) * lw[o];
  }
  __shared__ float sh[256];
  sh[threadIdx.x] = hv;
  __syncthreads();
  for (int st = 128; st > 0; st >>= 1) { if (threadIdx.x < st) sh[threadIdx.x] += sh[threadIdx.x+st]; __syncthreads(); }
  if (threadIdx.x == 0) out[b] = sh[0];
}

// ================= host =================
extern "C" void kernel_launch(void* const* d_in, const int* in_sizes, int n_in,
                              void* d_out, int out_size, void* d_ws, size_t ws_size,
                              hipStream_t stream) {
  const int*   q    = (const int*)d_in[0];
  const int*   wrel = (const int*)d_in[1];
  const int*   rrel = (const int*)d_in[2];
  const int*   wprv = (const int*)d_in[3];
  const int*   rprv = (const int*)d_in[4];
  const float* we   = (const float*)d_in[5];
  const float* re   = (const float*)d_in[6];
  const float* Wih_f= (const float*)d_in[7];
  const float* Whh_f= (const float*)d_in[8];
  const float* b_f  = (const float*)d_in[9];
  const float* Wih_b= (const float*)d_in[10];
  const float* Whh_b= (const float*)d_in[11];
  const float* b_b  = (const float*)d_in[12];
  const float* W    = (const float*)d_in[13];
  const float* c1w  = (const float*)d_in[14];
  const float* c1b  = (const float*)d_in[15];
  const float* c2w  = (const float*)d_in[16];
  const float* c2b  = (const float*)d_in[17];
  const float* c3w  = (const float*)d_in[18];
  const float* c3b  = (const float*)d_in[19];
  const float* lw   = (const float*)d_in[20];
  const float* l2w  = (const float*)d_in[21];
  const float* l2b  = (const float*)d_in[22];
  float* out = (float*)d_out;
  float* ws  = (float*)d_ws;

  unsigned short* WHB = (unsigned short*)(ws + OFF_WQ);
  float* B2   = ws + OFF_B2;
  unsigned short* XB3T  = (unsigned short*)(ws + OFF_XB3T);
  unsigned short* WB3T  = (unsigned short*)(ws + OFF_WB3T);
  unsigned short* L2B3T = (unsigned short*)(ws + OFF_L2B3T);
  unsigned short* CB3T  = (unsigned short*)(ws + OFF_CB3T);
  unsigned short* Xhi   = (unsigned short*)(ws + OFF_XHI);
  unsigned short* Xlo   = (unsigned short*)(ws + OFF_XLO);
  float* XP   = ws + OFF_XP;
  float* HSQ  = ws + OFF_HSQ;
  float* HSWP = ws + OFF_HSWP;
  float* HSRP = ws + OFF_HSRP;
  float* HSWR = ws + OFF_HSWR;
  float* HSRR = ws + OFF_HSRR;
  int*   flags = (int*)(ws + OFF_CS);                     // 3072 slots x 64B
  int*   det   = flags + 49152;                           // 128 slots x 64B
  float* RELP = ws + OFF_RELP;
  float* RELC = ws + OFF_RELC;
  float* RELW = ws + OFF_RELW;
  float* EN   = ws + OFF_EN;
  // During k_steps: HxA = RELP..RELW (96 slots x 32768 ush), HxB = XB3T (48 slots).
  unsigned short* HxA = (unsigned short*)(ws + OFF_RELP);
  unsigned short* HxB = (unsigned short*)(ws + OFF_XB3T);
  // XP-region aliases (XP dead after k_steps)
  float* QO1  = XP;
  float* ATT  = XP + 1310720;
  float* QO2  = XP + 2621440;
  unsigned short* Dhi  = (unsigned short*)(XP + 3932160);
  unsigned short* Dlo  = (unsigned short*)(XP + 4587520);
  unsigned short* RPhi = (unsigned short*)(XP + 5242880);
  unsigned short* RPlo = (unsigned short*)(XP + 5505024);
  unsigned short* RChi = (unsigned short*)(XP + 5767168);
  unsigned short* RClo = (unsigned short*)(XP + 6029312);
  unsigned short* M2hi = (unsigned short*)(XP + 5242880);   // overwrites RP/RC (dead by then)
  unsigned short* M2lo = (unsigned short*)(XP + 6555904);   // ends 7868928
  float* Y    = XP;   // conv tap-GEMM out [2560][1408]; QO1/ATT/QO2/D dead by conv time

  k_prep<<<14344, 256, 0, stream>>>(Whh_f, Whh_b, b_f, b_b, Wih_f, Wih_b, W, l2w,
                                    c1w, c2w, c3w,
                                    WHB, B2, XB3T, WB3T, L2B3T, CB3T, flags);
  k_gather<<<NTOK, 320, 0, stream>>>(q, wrel, rrel, wprv, rprv, we, re, Xhi, Xlo);
  { dim3 g(36, 16); k_bgemm<true><<<g, 256, 0, stream>>>(Xhi, Xlo, 320, XB3T, B2, XP, 2048, 320); }

  // ---- all 40 recurrent steps in one persistent kernel (unique slots, XCD fast path) ----
  k_steps<<<128, 256, 0, stream>>>(WHB, XP, HSQ, HSWP, HSRP, HSWR, HSRR, HxA, HxB, flags, det);

  k_qo1<<<5120, 256, 0, stream>>>(HSQ, QO1);
  k_rel<<<4096, 256, 0, stream>>>(HSWP, HSRP, HSWR, HSRR, RELP, RELC, RPhi, RPlo, RChi, RClo);

  // ---- attention (previous hop) ----
  { dim3 g(16, 8); k_mgemm<false><<<g, 256, 0, stream>>>(RPhi, RPlo, 512, WB3T, nullptr, RELW, 512, 512); }
  k_energy<<<160, 256, 0, stream>>>(RELW, QO1, EN);
  k_softmax<<<64, 256, 0, stream>>>(EN);
  k_atten<<<5120, 256, 0, stream>>>(EN, RELP, ATT);
  k_sub<<<5120, 256, 0, stream>>>(QO1, ATT, Dhi, Dlo);
  { dim3 g(40, 8); k_mgemm<true><<<g, 256, 0, stream>>>(Dhi, Dlo, 512, L2B3T, l2b, QO2, 512, 512); }

  // ---- attention (current relation) ----
  { dim3 g(16, 8); k_mgemm<false><<<g, 256, 0, stream>>>(RChi, RClo, 512, WB3T, nullptr, RELW, 512, 512); }
  k_energy<<<160, 256, 0, stream>>>(RELW, QO2, EN);
  k_softmax<<<64, 256, 0, stream>>>(EN);
  k_atten<<<5120, 256, 0, stream>>>(EN, RELC, ATT);

  // ---- convs: single tap-expanded 128^2 MFMA GEMM, then shifted pool ----
  k_m2<<<10258, 256, 0, stream>>>(QO2, ATT, M2hi, M2lo);
  { dim3 g(20, 11); k_bgemm<false><<<g, 256, 0, stream>>>(M2hi, M2lo, 1024, CB3T, nullptr, Y, 1408, 1024); }
  k_pool<<<64, 256, 0, stream>>>(Y, c1b, c2b, c3b, lw, out);
}